// Round 6
// baseline (706.008 us; speedup 1.0000x reference)
//
#include <hip/hip_runtime.h>

#define NN 100000     // nodes
#define NE 1600000    // edges
#define FIN 100
#define D 64
#define NCONV 4
#define NG 500
#define SCAN_T 512
#define NB0 ((NN + SCAN_T - 1) / SCAN_T)   // 196

typedef unsigned int uint;
typedef unsigned short ushort;

// f32 -> bf16 round-to-nearest-even
__device__ inline ushort f2bf(float x) {
    uint u = __float_as_uint(x);
    u += 0x7fffu + ((u >> 16) & 1u);
    return (ushort)(u >> 16);
}
__device__ inline float bflo(uint u) { return __uint_as_float(u << 16); }
__device__ inline float bfhi(uint u) { return __uint_as_float(u & 0xffff0000u); }
__device__ inline float bf2f(ushort s) { return __uint_as_float((uint)s << 16); }

// ---------------- rank histogram: rank[e] = running count per dst ----------------
__global__ void k_rank(const int* __restrict__ col, int* __restrict__ counts,
                       int* __restrict__ rank) {
    int e = blockIdx.x * blockDim.x + threadIdx.x;
    if (e < NE) rank[e] = atomicAdd(&counts[col[e]], 1);
}

// ---------------- two-level exclusive scan of counts -> rowstart ----------------
__global__ __launch_bounds__(SCAN_T) void k_scan1(const int* __restrict__ counts,
                                                  int* __restrict__ rowstart,
                                                  int* __restrict__ bsums) {
    __shared__ int sh[SCAN_T];
    int t = threadIdx.x, i = blockIdx.x * SCAN_T + t;
    int v = (i < NN) ? counts[i] : 0;
    sh[t] = v;
    __syncthreads();
    for (int off = 1; off < SCAN_T; off <<= 1) {
        int u = (t >= off) ? sh[t - off] : 0;
        __syncthreads();
        sh[t] += u;
        __syncthreads();
    }
    if (i < NN) rowstart[i] = sh[t] - v;      // exclusive
    if (t == SCAN_T - 1) bsums[blockIdx.x] = sh[t];
}

__global__ __launch_bounds__(256) void k_scan2(int* __restrict__ bsums) {
    __shared__ int sh[256];
    int t = threadIdx.x;
    int v = (t < NB0) ? bsums[t] : 0;
    sh[t] = v;
    __syncthreads();
    for (int off = 1; off < 256; off <<= 1) {
        int u = (t >= off) ? sh[t - off] : 0;
        __syncthreads();
        sh[t] += u;
        __syncthreads();
    }
    if (t < NB0) bsums[t] = sh[t] - v;        // exclusive over block sums
}

__global__ __launch_bounds__(SCAN_T) void k_scan3(int* __restrict__ rowstart,
                                                  const int* __restrict__ bsums) {
    int i = blockIdx.x * SCAN_T + threadIdx.x;
    if (i < NN) rowstart[i] += bsums[blockIdx.x];
    if (i == 0) rowstart[NN] = NE;
}

// ---------------- CSR fill (no atomics): slot = rowstart[c] + rank[e] ----------
__global__ void k_fill(const int* __restrict__ row, const int* __restrict__ col,
                       const float* __restrict__ ew, const int* __restrict__ rank,
                       const int* __restrict__ rowstart, int2* __restrict__ csr) {
    int e = blockIdx.x * blockDim.x + threadIdx.x;
    if (e >= NE) return;
    int slot = rowstart[col[e]] + rank[e];
    csr[slot] = make_int2(row[e], __float_as_int(ew[e]));
}

// ---------------- per-node degree from CSR row sum -> dis = deg^{-1/2} --------
__global__ void k_rowdeg(const int2* __restrict__ csr, const int* __restrict__ rowstart,
                         float* __restrict__ dis) {
    int i = blockIdx.x * blockDim.x + threadIdx.x;
    if (i >= NN) return;
    int e0 = rowstart[i], e1 = rowstart[i + 1];
    float d = 0.f;
    for (int s = e0; s < e1; ++s) d += __int_as_float(csr[s].y);
    dis[i] = (d > 0.f) ? (1.0f / sqrtf(d)) : 0.f;
}

// ---------------- convert csr weight: ew -> dis[src]*ew*dis[dst] --------------
__global__ void k_rownorm(int2* __restrict__ csr, const int* __restrict__ rowstart,
                          const float* __restrict__ dis) {
    int i = blockIdx.x * blockDim.x + threadIdx.x;
    if (i >= NN) return;
    int e0 = rowstart[i], e1 = rowstart[i + 1];
    float dc = dis[i];
    for (int s = e0; s < e1; ++s) {
        int2 p = csr[s];
        float w = dis[p.x] * __int_as_float(p.y) * dc;
        csr[s].y = __float_as_int(w);
    }
}

// ---------------- lin0: out = relu(x @ W0 + b0) -> bf16 rows ------------------
__global__ __launch_bounds__(256) void k_lin0(const float* __restrict__ x,
                                              const float* __restrict__ w,
                                              const float* __restrict__ b,
                                              ushort* __restrict__ out) {
    __shared__ float ws[FIN * D];     // 25.6 KB
    __shared__ float xs[16][FIN];     // 6.4 KB
    int t = threadIdx.x;
    for (int i = t; i < FIN * D; i += 256) ws[i] = w[i];
    int r0 = blockIdx.x * 16;
    for (int i = t; i < 16 * FIN; i += 256) {
        int rr = i / FIN, kk = i - rr * FIN;
        xs[rr][kk] = x[(r0 + rr) * FIN + kk];   // NN % 16 == 0
    }
    __syncthreads();
    int wave = t >> 6, lane = t & 63;
    float bv = b[lane];
    for (int ri = wave; ri < 16; ri += 4) {
        float acc = bv;
        #pragma unroll
        for (int k = 0; k < FIN; k += 4) {
            float4 xv = *reinterpret_cast<const float4*>(&xs[ri][k]);
            acc = fmaf(xv.x, ws[(k + 0) * D + lane], acc);
            acc = fmaf(xv.y, ws[(k + 1) * D + lane], acc);
            acc = fmaf(xv.z, ws[(k + 2) * D + lane], acc);
            acc = fmaf(xv.w, ws[(k + 3) * D + lane], acc);
        }
        out[(r0 + ri) * D + lane] = f2bf(fmaxf(acc, 0.f));
    }
}

// ---------------- aggregation: dst[n] = sum_e w_e * src[csr_src[e]]  (bf16 rows)
// 4 nodes per wave, 16 lanes per node; lane privately owns 4 features.
// No LDS, no shuffles; unroll 4 -> 4 gathers (2KB) in flight per wave.
__global__ __launch_bounds__(256) void k_agg(const ushort* __restrict__ src,
                                             const int* __restrict__ rowstart,
                                             const int2* __restrict__ csr,
                                             ushort* __restrict__ dst) {
    int t = threadIdx.x;
    int lane = t & 63;
    int g = lane >> 4;          // node sub-index within wave
    int f = lane & 15;          // feature quad
    int node = blockIdx.x * 16 + (t >> 6) * 4 + g;   // NN % 16 == 0
    int e0 = rowstart[node], e1 = rowstart[node + 1];
    float4 acc = {0.f, 0.f, 0.f, 0.f};
    for (int e = e0; __any(e < e1); e += 4) {
        #pragma unroll
        for (int u = 0; u < 4; ++u) {
            int ee = e + u;
            bool valid = (ee < e1);
            int idx = valid ? ee : 0;
            int2 p = csr[idx];
            float wv = valid ? __int_as_float(p.y) : 0.f;
            uint2 v = *reinterpret_cast<const uint2*>(&src[p.x * D + f * 4]);
            acc.x = fmaf(bflo(v.x), wv, acc.x);
            acc.y = fmaf(bfhi(v.x), wv, acc.y);
            acc.z = fmaf(bflo(v.y), wv, acc.z);
            acc.w = fmaf(bfhi(v.y), wv, acc.w);
        }
    }
    uint2 o;
    o.x = (uint)f2bf(acc.x) | ((uint)f2bf(acc.y) << 16);
    o.y = (uint)f2bf(acc.z) | ((uint)f2bf(acc.w) << 16);
    *reinterpret_cast<uint2*>(&dst[node * D + f * 4]) = o;
}

// ---------------- dense: out = relu(a @ W + b), a bf16 [N,64], W f32 in VGPRs
// lane = output feature; W column held in 64 VGPRs; a-row broadcast via shfl.
#define DN_PW 16   // nodes per wave
__global__ __launch_bounds__(256) void k_dense(const ushort* __restrict__ a,
                                               const float* __restrict__ w,
                                               const float* __restrict__ bias,
                                               ushort* __restrict__ out) {
    int lane = threadIdx.x & 63;
    int wid = threadIdx.x >> 6;
    float Wreg[D];
    #pragma unroll
    for (int k = 0; k < D; ++k) Wreg[k] = w[k * D + lane];
    float bv = bias[lane];
    int n0 = blockIdx.x * (4 * DN_PW) + wid * DN_PW;
    int nend = n0 + DN_PW;
    if (nend > NN) nend = NN;
    for (int n = n0; n < nend; ++n) {
        float av = bf2f(a[n * D + lane]);
        float o0 = bv, o1 = 0.f, o2 = 0.f, o3 = 0.f;
        #pragma unroll
        for (int k = 0; k < D; k += 4) {
            o0 = fmaf(__shfl(av, k + 0), Wreg[k + 0], o0);
            o1 = fmaf(__shfl(av, k + 1), Wreg[k + 1], o1);
            o2 = fmaf(__shfl(av, k + 2), Wreg[k + 2], o2);
            o3 = fmaf(__shfl(av, k + 3), Wreg[k + 3], o3);
        }
        float o = (o0 + o1) + (o2 + o3);
        out[n * D + lane] = f2bf(fmaxf(o, 0.f));
    }
}

// ---------------- segmented mean-pool over sorted batch (bf16 src) ------------
__global__ __launch_bounds__(256) void k_pool(const ushort* __restrict__ src,
                                              const int* __restrict__ batch,
                                              float* __restrict__ pooled,
                                              float* __restrict__ cnt) {
    int wave = threadIdx.x >> 6, lane = threadIdx.x & 63;
    int n0 = blockIdx.x * 64 + wave * 16;
    float s = 0.f;
    int curg = -1, runlen = 0;
    for (int i = 0; i < 16; ++i) {
        int node = n0 + i;
        if (node >= NN) break;
        int gg = batch[node];
        if (gg != curg) {
            if (curg >= 0) {
                atomicAdd(&pooled[curg * D + lane], s);
                if (lane == 0) atomicAdd(&cnt[curg], (float)runlen);
            }
            curg = gg; s = 0.f; runlen = 0;
        }
        s += bf2f(src[node * D + lane]);
        ++runlen;
    }
    if (curg >= 0) {
        atomicAdd(&pooled[curg * D + lane], s);
        if (lane == 0) atomicAdd(&cnt[curg], (float)runlen);
    }
}

// ---------------- MLP head: one block per graph ----------------
__global__ __launch_bounds__(64) void k_head(const float* __restrict__ pooled,
                                             const float* __restrict__ cnt,
                                             const float* __restrict__ lin1_w,
                                             const float* __restrict__ lin1_b,
                                             const float* __restrict__ fc_w,
                                             const float* __restrict__ fc_b,
                                             const float* __restrict__ lin2_w,
                                             const float* __restrict__ lin2_b,
                                             float* __restrict__ out) {
    __shared__ float buf0[D], buf1[D];
    int g = blockIdx.x, d = threadIdx.x;
    float c = fmaxf(cnt[g], 1.0f);
    buf0[d] = pooled[g * D + d] / c;
    __syncthreads();
    float acc = lin1_b[d];
    #pragma unroll
    for (int k = 0; k < D; ++k) acc += buf0[k] * lin1_w[k * D + d];
    buf1[d] = fmaxf(acc, 0.f);
    __syncthreads();
    acc = fc_b[d];
    #pragma unroll
    for (int k = 0; k < D; ++k) acc += buf1[k] * fc_w[k * D + d];
    buf0[d] = fmaxf(acc, 0.f);
    __syncthreads();
    acc = fc_b[D + d];
    #pragma unroll
    for (int k = 0; k < D; ++k) acc += buf0[k] * fc_w[D * D + k * D + d];
    buf1[d] = fmaxf(acc, 0.f);
    __syncthreads();
    float v = buf1[d] * lin2_w[d];
    #pragma unroll
    for (int off = 32; off; off >>= 1) v += __shfl_down(v, off);
    if (d == 0) out[g] = v + lin2_b[0];
}

extern "C" void kernel_launch(void* const* d_in, const int* in_sizes, int n_in,
                              void* d_out, int out_size, void* d_ws, size_t ws_size,
                              hipStream_t stream) {
    const float* x      = (const float*)d_in[0];
    const int*   ei     = (const int*)  d_in[1];
    const float* ew     = (const float*)d_in[2];
    const int*   batch  = (const int*)  d_in[3];
    const float* lin0_w = (const float*)d_in[4];
    const float* lin0_b = (const float*)d_in[5];
    const float* conv_w = (const float*)d_in[6];
    const float* conv_b = (const float*)d_in[7];
    const float* lin1_w = (const float*)d_in[8];
    const float* lin1_b = (const float*)d_in[9];
    const float* fc_w   = (const float*)d_in[10];
    const float* fc_b   = (const float*)d_in[11];
    const float* lin2_w = (const float*)d_in[12];
    const float* lin2_b = (const float*)d_in[13];
    float* out = (float*)d_out;

    const int* rowv = ei;
    const int* colv = ei + NE;

    // workspace layout (~53 MB)
    ushort* bufA    = (ushort*)d_ws;                  // N*D bf16 (12.8 MB)
    ushort* bufB    = bufA + (size_t)NN * D;          // N*D bf16
    ushort* bufG    = bufB + (size_t)NN * D;          // N*D bf16 (agg scratch)
    int2*   csr     = (int2*)(bufG + (size_t)NN * D); // E (src, weight-bits)
    int*   rowstart = (int*)(csr + NE);               // N+1
    float* dis      = (float*)(rowstart + NN + 1);    // N
    int*   counts   = (int*)(dis + NN);               // N
    int*   bsums    = counts + NN;                    // 256
    float* pooled   = (float*)(bsums + 256);          // G*D
    float* cnt      = pooled + NG * D;                // G
    int*   rank     = (int*)bufB;                     // E ints, overlays bufB (dead until conv1 dense)

    hipMemsetAsync(counts, 0, NN * sizeof(int), stream);
    hipMemsetAsync(pooled, 0, (NG * D + NG) * sizeof(float), stream);

    k_rank<<<(NE + 255) / 256, 256, 0, stream>>>(colv, counts, rank);
    k_scan1<<<NB0, SCAN_T, 0, stream>>>(counts, rowstart, bsums);
    k_scan2<<<1, 256, 0, stream>>>(bsums);
    k_scan3<<<NB0, SCAN_T, 0, stream>>>(rowstart, bsums);
    k_fill<<<(NE + 255) / 256, 256, 0, stream>>>(rowv, colv, ew, rank, rowstart, csr);
    k_rowdeg<<<(NN + 255) / 256, 256, 0, stream>>>(csr, rowstart, dis);
    k_rownorm<<<(NN + 255) / 256, 256, 0, stream>>>(csr, rowstart, dis);

    k_lin0<<<NN / 16, 256, 0, stream>>>(x, lin0_w, lin0_b, bufA);

    int dense_grid = (NN + 4 * DN_PW - 1) / (4 * DN_PW);
    // conv1: A -> G -> B
    k_agg<<<NN / 16, 256, 0, stream>>>(bufA, rowstart, csr, bufG);
    k_dense<<<dense_grid, 256, 0, stream>>>(bufG, conv_w + 0 * D * D, conv_b + 0 * D, bufB);
    // conv2: B -> G -> A
    k_agg<<<NN / 16, 256, 0, stream>>>(bufB, rowstart, csr, bufG);
    k_dense<<<dense_grid, 256, 0, stream>>>(bufG, conv_w + 1 * D * D, conv_b + 1 * D, bufA);
    // conv3: A -> G -> B
    k_agg<<<NN / 16, 256, 0, stream>>>(bufA, rowstart, csr, bufG);
    k_dense<<<dense_grid, 256, 0, stream>>>(bufG, conv_w + 2 * D * D, conv_b + 2 * D, bufB);
    // conv4: B -> G -> A
    k_agg<<<NN / 16, 256, 0, stream>>>(bufB, rowstart, csr, bufG);
    k_dense<<<dense_grid, 256, 0, stream>>>(bufG, conv_w + 3 * D * D, conv_b + 3 * D, bufA);

    k_pool<<<(NN + 63) / 64, 256, 0, stream>>>(bufA, batch, pooled, cnt);
    k_head<<<NG, 64, 0, stream>>>(pooled, cnt, lin1_w, lin1_b, fc_w, fc_b,
                                  lin2_w, lin2_b, out);
}

// Round 7
// 431.950 us; speedup vs baseline: 1.6345x; 1.6345x over previous
//
#include <hip/hip_runtime.h>

#define NN 100000     // nodes
#define NE 1600000    // edges
#define FIN 100
#define D 64
#define NCONV 4
#define NG 500
#define SCAN_T 512
#define NB0 ((NN + SCAN_T - 1) / SCAN_T)   // 196

typedef unsigned int uint;
typedef unsigned short ushort;
typedef __attribute__((ext_vector_type(8))) short bf16x8;
typedef __attribute__((ext_vector_type(4))) float f32x4;

// f32 -> bf16 round-to-nearest-even
__device__ inline ushort f2bf(float x) {
    uint u = __float_as_uint(x);
    u += 0x7fffu + ((u >> 16) & 1u);
    return (ushort)(u >> 16);
}
__device__ inline float bflo(uint u) { return __uint_as_float(u << 16); }
__device__ inline float bfhi(uint u) { return __uint_as_float(u & 0xffff0000u); }
__device__ inline float bf2f(ushort s) { return __uint_as_float((uint)s << 16); }

// ---------------- rank histogram: rank[e] = running count per dst ----------------
__global__ void k_rank(const int* __restrict__ col, int* __restrict__ counts,
                       int* __restrict__ rank) {
    int e = blockIdx.x * blockDim.x + threadIdx.x;
    if (e < NE) rank[e] = atomicAdd(&counts[col[e]], 1);
}

// ---------------- two-level exclusive scan of counts -> rowstart ----------------
__global__ __launch_bounds__(SCAN_T) void k_scan1(const int* __restrict__ counts,
                                                  int* __restrict__ rowstart,
                                                  int* __restrict__ bsums) {
    __shared__ int sh[SCAN_T];
    int t = threadIdx.x, i = blockIdx.x * SCAN_T + t;
    int v = (i < NN) ? counts[i] : 0;
    sh[t] = v;
    __syncthreads();
    for (int off = 1; off < SCAN_T; off <<= 1) {
        int u = (t >= off) ? sh[t - off] : 0;
        __syncthreads();
        sh[t] += u;
        __syncthreads();
    }
    if (i < NN) rowstart[i] = sh[t] - v;      // exclusive
    if (t == SCAN_T - 1) bsums[blockIdx.x] = sh[t];
}

__global__ __launch_bounds__(256) void k_scan2(int* __restrict__ bsums) {
    __shared__ int sh[256];
    int t = threadIdx.x;
    int v = (t < NB0) ? bsums[t] : 0;
    sh[t] = v;
    __syncthreads();
    for (int off = 1; off < 256; off <<= 1) {
        int u = (t >= off) ? sh[t - off] : 0;
        __syncthreads();
        sh[t] += u;
        __syncthreads();
    }
    if (t < NB0) bsums[t] = sh[t] - v;        // exclusive over block sums
}

__global__ __launch_bounds__(SCAN_T) void k_scan3(int* __restrict__ rowstart,
                                                  const int* __restrict__ bsums) {
    int i = blockIdx.x * SCAN_T + threadIdx.x;
    if (i < NN) rowstart[i] += bsums[blockIdx.x];
    if (i == 0) rowstart[NN] = NE;
}

// ---------------- CSR fill (no atomics): slot = rowstart[c] + rank[e] ----------
__global__ void k_fill(const int* __restrict__ row, const int* __restrict__ col,
                       const float* __restrict__ ew, const int* __restrict__ rank,
                       const int* __restrict__ rowstart, int2* __restrict__ csr) {
    int e = blockIdx.x * blockDim.x + threadIdx.x;
    if (e >= NE) return;
    int slot = rowstart[col[e]] + rank[e];
    csr[slot] = make_int2(row[e], __float_as_int(ew[e]));
}

// ---------------- per-node degree from CSR row sum -> dis = deg^{-1/2} --------
__global__ void k_rowdeg(const int2* __restrict__ csr, const int* __restrict__ rowstart,
                         float* __restrict__ dis) {
    int i = blockIdx.x * blockDim.x + threadIdx.x;
    if (i >= NN) return;
    int e0 = rowstart[i], e1 = rowstart[i + 1];
    float d = 0.f;
    for (int s = e0; s < e1; ++s) d += __int_as_float(csr[s].y);
    dis[i] = (d > 0.f) ? (1.0f / sqrtf(d)) : 0.f;
}

// ---------------- convert csr weight: ew -> dis[src]*ew*dis[dst] --------------
__global__ void k_rownorm(int2* __restrict__ csr, const int* __restrict__ rowstart,
                          const float* __restrict__ dis) {
    int i = blockIdx.x * blockDim.x + threadIdx.x;
    if (i >= NN) return;
    int e0 = rowstart[i], e1 = rowstart[i + 1];
    float dc = dis[i];
    for (int s = e0; s < e1; ++s) {
        int2 p = csr[s];
        float w = dis[p.x] * __int_as_float(p.y) * dc;
        csr[s].y = __float_as_int(w);
    }
}

// ---------------- weight split into pre-swizzled MFMA fragments ----------------
// frag layout: [layer][ct:4][kh:2][h:2][lane:64][j:8] bf16
// value: W_l[k = kh*32 + (lane>>4)*8 + j][n = ct*16 + (lane&15)]
__global__ void k_wsplit(const float* __restrict__ conv_w, ushort* __restrict__ wf) {
    int tid = blockIdx.x * blockDim.x + threadIdx.x;   // 4*4*2*64*8 = 16384
    int j = tid & 7;
    int lane = (tid >> 3) & 63;
    int kh = (tid >> 9) & 1;
    int ct = (tid >> 10) & 3;
    int l = tid >> 12;
    int k = kh * 32 + (lane >> 4) * 8 + j;
    int n = ct * 16 + (lane & 15);
    float w = conv_w[l * D * D + k * D + n];
    ushort hi = f2bf(w);
    ushort lo = f2bf(w - bf2f(hi));
    int base = (((l * 4 + ct) * 2 + kh) * 2) * 512 + lane * 8 + j;
    wf[base] = hi;            // h=0
    wf[base + 512] = lo;      // h=1
}

// ---------------- lin0: out = relu(x @ W0 + b0) -> bf16 rows ------------------
__global__ __launch_bounds__(256) void k_lin0(const float* __restrict__ x,
                                              const float* __restrict__ w,
                                              const float* __restrict__ b,
                                              ushort* __restrict__ out) {
    __shared__ float ws[FIN * D];     // 25.6 KB
    __shared__ float xs[16][FIN];     // 6.4 KB
    int t = threadIdx.x;
    for (int i = t; i < FIN * D; i += 256) ws[i] = w[i];
    int r0 = blockIdx.x * 16;
    for (int i = t; i < 16 * FIN; i += 256) {
        int rr = i / FIN, kk = i - rr * FIN;
        xs[rr][kk] = x[(r0 + rr) * FIN + kk];   // NN % 16 == 0
    }
    __syncthreads();
    int wave = t >> 6, lane = t & 63;
    float bv = b[lane];
    for (int ri = wave; ri < 16; ri += 4) {
        float acc = bv;
        #pragma unroll
        for (int k = 0; k < FIN; k += 4) {
            float4 xv = *reinterpret_cast<const float4*>(&xs[ri][k]);
            acc = fmaf(xv.x, ws[(k + 0) * D + lane], acc);
            acc = fmaf(xv.y, ws[(k + 1) * D + lane], acc);
            acc = fmaf(xv.z, ws[(k + 2) * D + lane], acc);
            acc = fmaf(xv.w, ws[(k + 3) * D + lane], acc);
        }
        out[(r0 + ri) * D + lane] = f2bf(fmaxf(acc, 0.f));
    }
}

// ---------------- aggregation: dst[n] = sum_e w_e * src[csr_src[e]]  (bf16 rows)
__global__ __launch_bounds__(256) void k_agg(const ushort* __restrict__ src,
                                             const int* __restrict__ rowstart,
                                             const int2* __restrict__ csr,
                                             ushort* __restrict__ dst) {
    int t = threadIdx.x;
    int lane = t & 63;
    int g = lane >> 4;          // node sub-index within wave
    int f = lane & 15;          // feature quad
    int node = blockIdx.x * 16 + (t >> 6) * 4 + g;   // NN % 16 == 0
    int e0 = rowstart[node], e1 = rowstart[node + 1];
    float4 acc = {0.f, 0.f, 0.f, 0.f};
    for (int e = e0; __any(e < e1); e += 4) {
        #pragma unroll
        for (int u = 0; u < 4; ++u) {
            int ee = e + u;
            bool valid = (ee < e1);
            int idx = valid ? ee : 0;
            int2 p = csr[idx];
            float wv = valid ? __int_as_float(p.y) : 0.f;
            uint2 v = *reinterpret_cast<const uint2*>(&src[p.x * D + f * 4]);
            acc.x = fmaf(bflo(v.x), wv, acc.x);
            acc.y = fmaf(bfhi(v.x), wv, acc.y);
            acc.z = fmaf(bflo(v.y), wv, acc.z);
            acc.w = fmaf(bfhi(v.y), wv, acc.w);
        }
    }
    uint2 o;
    o.x = (uint)f2bf(acc.x) | ((uint)f2bf(acc.y) << 16);
    o.y = (uint)f2bf(acc.z) | ((uint)f2bf(acc.w) << 16);
    *reinterpret_cast<uint2*>(&dst[node * D + f * 4]) = o;
}

// ---------------- dense via MFMA: out = relu(a @ (Whi+Wlo) + b), bf16 in/out --
// block = 256 (4 waves); wave handles one 16-row tile; grid = ceil(N/64).
__global__ __launch_bounds__(256) void k_mfma_dense(const ushort* __restrict__ a,
                                                    const ushort* __restrict__ wf,
                                                    const float* __restrict__ bias,
                                                    ushort* __restrict__ out) {
    int t = threadIdx.x;
    int wave = t >> 6, lane = t & 63;
    // load weight fragments (per-lane 16B each)
    bf16x8 wh[4][2], wl[4][2];
    #pragma unroll
    for (int ct = 0; ct < 4; ++ct)
        #pragma unroll
        for (int kh = 0; kh < 2; ++kh) {
            int base = ((ct * 2 + kh) * 2) * 512 + lane * 8;
            wh[ct][kh] = *reinterpret_cast<const bf16x8*>(&wf[base]);
            wl[ct][kh] = *reinterpret_cast<const bf16x8*>(&wf[base + 512]);
        }
    float bias_v[4];
    #pragma unroll
    for (int ct = 0; ct < 4; ++ct) bias_v[ct] = bias[ct * 16 + (lane & 15)];

    int r = blockIdx.x * 64 + wave * 16;      // 16-row tile (NN % 16 == 0)
    if (r >= NN) return;
    int arow = r + (lane & 15);
    bf16x8 a0 = *reinterpret_cast<const bf16x8*>(&a[arow * D + (lane >> 4) * 8]);
    bf16x8 a1 = *reinterpret_cast<const bf16x8*>(&a[arow * D + 32 + (lane >> 4) * 8]);

    f32x4 acc[4];
    #pragma unroll
    for (int ct = 0; ct < 4; ++ct) {
        acc[ct] = {bias_v[ct], bias_v[ct], bias_v[ct], bias_v[ct]};
        acc[ct] = __builtin_amdgcn_mfma_f32_16x16x32_bf16(a0, wh[ct][0], acc[ct], 0, 0, 0);
        acc[ct] = __builtin_amdgcn_mfma_f32_16x16x32_bf16(a1, wh[ct][1], acc[ct], 0, 0, 0);
        acc[ct] = __builtin_amdgcn_mfma_f32_16x16x32_bf16(a0, wl[ct][0], acc[ct], 0, 0, 0);
        acc[ct] = __builtin_amdgcn_mfma_f32_16x16x32_bf16(a1, wl[ct][1], acc[ct], 0, 0, 0);
    }
    // C layout: col = ct*16 + (lane&15), row = r + (lane>>4)*4 + i
    #pragma unroll
    for (int ct = 0; ct < 4; ++ct) {
        int ocol = ct * 16 + (lane & 15);
        #pragma unroll
        for (int i = 0; i < 4; ++i) {
            int orow = r + (lane >> 4) * 4 + i;
            out[orow * D + ocol] = f2bf(fmaxf(acc[ct][i], 0.f));
        }
    }
}

// ---------------- segmented mean-pool over sorted batch (bf16 src) ------------
__global__ __launch_bounds__(256) void k_pool(const ushort* __restrict__ src,
                                              const int* __restrict__ batch,
                                              float* __restrict__ pooled,
                                              float* __restrict__ cnt) {
    int wave = threadIdx.x >> 6, lane = threadIdx.x & 63;
    int n0 = blockIdx.x * 64 + wave * 16;
    float s = 0.f;
    int curg = -1, runlen = 0;
    for (int i = 0; i < 16; ++i) {
        int node = n0 + i;
        if (node >= NN) break;
        int gg = batch[node];
        if (gg != curg) {
            if (curg >= 0) {
                atomicAdd(&pooled[curg * D + lane], s);
                if (lane == 0) atomicAdd(&cnt[curg], (float)runlen);
            }
            curg = gg; s = 0.f; runlen = 0;
        }
        s += bf2f(src[node * D + lane]);
        ++runlen;
    }
    if (curg >= 0) {
        atomicAdd(&pooled[curg * D + lane], s);
        if (lane == 0) atomicAdd(&cnt[curg], (float)runlen);
    }
}

// ---------------- MLP head: one block per graph ----------------
__global__ __launch_bounds__(64) void k_head(const float* __restrict__ pooled,
                                             const float* __restrict__ cnt,
                                             const float* __restrict__ lin1_w,
                                             const float* __restrict__ lin1_b,
                                             const float* __restrict__ fc_w,
                                             const float* __restrict__ fc_b,
                                             const float* __restrict__ lin2_w,
                                             const float* __restrict__ lin2_b,
                                             float* __restrict__ out) {
    __shared__ float buf0[D], buf1[D];
    int g = blockIdx.x, d = threadIdx.x;
    float c = fmaxf(cnt[g], 1.0f);
    buf0[d] = pooled[g * D + d] / c;
    __syncthreads();
    float acc = lin1_b[d];
    #pragma unroll
    for (int k = 0; k < D; ++k) acc += buf0[k] * lin1_w[k * D + d];
    buf1[d] = fmaxf(acc, 0.f);
    __syncthreads();
    acc = fc_b[d];
    #pragma unroll
    for (int k = 0; k < D; ++k) acc += buf1[k] * fc_w[k * D + d];
    buf0[d] = fmaxf(acc, 0.f);
    __syncthreads();
    acc = fc_b[D + d];
    #pragma unroll
    for (int k = 0; k < D; ++k) acc += buf0[k] * fc_w[D * D + k * D + d];
    buf1[d] = fmaxf(acc, 0.f);
    __syncthreads();
    float v = buf1[d] * lin2_w[d];
    #pragma unroll
    for (int off = 32; off; off >>= 1) v += __shfl_down(v, off);
    if (d == 0) out[g] = v + lin2_b[0];
}

extern "C" void kernel_launch(void* const* d_in, const int* in_sizes, int n_in,
                              void* d_out, int out_size, void* d_ws, size_t ws_size,
                              hipStream_t stream) {
    const float* x      = (const float*)d_in[0];
    const int*   ei     = (const int*)  d_in[1];
    const float* ew     = (const float*)d_in[2];
    const int*   batch  = (const int*)  d_in[3];
    const float* lin0_w = (const float*)d_in[4];
    const float* lin0_b = (const float*)d_in[5];
    const float* conv_w = (const float*)d_in[6];
    const float* conv_b = (const float*)d_in[7];
    const float* lin1_w = (const float*)d_in[8];
    const float* lin1_b = (const float*)d_in[9];
    const float* fc_w   = (const float*)d_in[10];
    const float* fc_b   = (const float*)d_in[11];
    const float* lin2_w = (const float*)d_in[12];
    const float* lin2_b = (const float*)d_in[13];
    float* out = (float*)d_out;

    const int* rowv = ei;
    const int* colv = ei + NE;

    // workspace layout (~53 MB)
    ushort* bufA    = (ushort*)d_ws;                  // N*D bf16 (12.8 MB)
    ushort* bufB    = bufA + (size_t)NN * D;          // N*D bf16
    ushort* bufG    = bufB + (size_t)NN * D;          // N*D bf16 (agg scratch)
    int2*   csr     = (int2*)(bufG + (size_t)NN * D); // E (src, weight-bits)
    int*   rowstart = (int*)(csr + NE);               // N+1
    float* dis      = (float*)(rowstart + NN + 1);    // N
    int*   counts   = (int*)(dis + NN);               // N
    int*   bsums    = counts + NN;                    // 256
    float* pooled   = (float*)(bsums + 256);          // G*D
    float* cnt      = pooled + NG * D;                // G
    ushort* wfrags  = (ushort*)(cnt + NG);            // 4*8192 bf16 = 64 KB
    int*   rank     = (int*)bufB;                     // E ints, overlays bufB

    hipMemsetAsync(counts, 0, NN * sizeof(int), stream);
    hipMemsetAsync(pooled, 0, (NG * D + NG) * sizeof(float), stream);

    k_rank<<<(NE + 255) / 256, 256, 0, stream>>>(colv, counts, rank);
    k_scan1<<<NB0, SCAN_T, 0, stream>>>(counts, rowstart, bsums);
    k_scan2<<<1, 256, 0, stream>>>(bsums);
    k_scan3<<<NB0, SCAN_T, 0, stream>>>(rowstart, bsums);
    k_fill<<<(NE + 255) / 256, 256, 0, stream>>>(rowv, colv, ew, rank, rowstart, csr);
    k_rowdeg<<<(NN + 255) / 256, 256, 0, stream>>>(csr, rowstart, dis);
    k_rownorm<<<(NN + 255) / 256, 256, 0, stream>>>(csr, rowstart, dis);
    k_wsplit<<<64, 256, 0, stream>>>(conv_w, wfrags);

    k_lin0<<<NN / 16, 256, 0, stream>>>(x, lin0_w, lin0_b, bufA);

    int dg = (NN + 63) / 64;
    // conv1: A -> G -> B
    k_agg<<<NN / 16, 256, 0, stream>>>(bufA, rowstart, csr, bufG);
    k_mfma_dense<<<dg, 256, 0, stream>>>(bufG, wfrags + 0 * 8192, conv_b + 0 * D, bufB);
    // conv2: B -> G -> A
    k_agg<<<NN / 16, 256, 0, stream>>>(bufB, rowstart, csr, bufG);
    k_mfma_dense<<<dg, 256, 0, stream>>>(bufG, wfrags + 1 * 8192, conv_b + 1 * D, bufA);
    // conv3: A -> G -> B
    k_agg<<<NN / 16, 256, 0, stream>>>(bufA, rowstart, csr, bufG);
    k_mfma_dense<<<dg, 256, 0, stream>>>(bufG, wfrags + 2 * 8192, conv_b + 2 * D, bufB);
    // conv4: B -> G -> A
    k_agg<<<NN / 16, 256, 0, stream>>>(bufB, rowstart, csr, bufG);
    k_mfma_dense<<<dg, 256, 0, stream>>>(bufG, wfrags + 3 * 8192, conv_b + 3 * D, bufA);

    k_pool<<<(NN + 63) / 64, 256, 0, stream>>>(bufA, batch, pooled, cnt);
    k_head<<<NG, 64, 0, stream>>>(pooled, cnt, lin1_w, lin1_b, fc_w, fc_b,
                                  lin2_w, lin2_b, out);
}

// Round 8
// 386.131 us; speedup vs baseline: 1.8284x; 1.1187x over previous
//
#include <hip/hip_runtime.h>

#define NN 100000     // nodes
#define NE 1600000    // edges
#define FIN 100
#define D 64
#define NCONV 4
#define NG 500
#define SCAN_T 512
#define NB0 ((NN + SCAN_T - 1) / SCAN_T)   // 196

typedef unsigned int uint;
typedef unsigned short ushort;
typedef __attribute__((ext_vector_type(8))) short bf16x8;
typedef __attribute__((ext_vector_type(4))) float f32x4;

// f32 -> bf16 round-to-nearest-even
__device__ inline ushort f2bf(float x) {
    uint u = __float_as_uint(x);
    u += 0x7fffu + ((u >> 16) & 1u);
    return (ushort)(u >> 16);
}
__device__ inline float bflo(uint u) { return __uint_as_float(u << 16); }
__device__ inline float bfhi(uint u) { return __uint_as_float(u & 0xffff0000u); }
__device__ inline float bf2f(ushort s) { return __uint_as_float((uint)s << 16); }

// ---------------- rank histogram: rank[e] = running count per dst ----------------
__global__ void k_rank(const int* __restrict__ col, int* __restrict__ counts,
                       int* __restrict__ rank) {
    int e = blockIdx.x * blockDim.x + threadIdx.x;
    if (e < NE) rank[e] = atomicAdd(&counts[col[e]], 1);
}

// ---------------- two-level exclusive scan of counts -> rowstart ----------------
__global__ __launch_bounds__(SCAN_T) void k_scan1(const int* __restrict__ counts,
                                                  int* __restrict__ rowstart,
                                                  int* __restrict__ bsums) {
    __shared__ int sh[SCAN_T];
    int t = threadIdx.x, i = blockIdx.x * SCAN_T + t;
    int v = (i < NN) ? counts[i] : 0;
    sh[t] = v;
    __syncthreads();
    for (int off = 1; off < SCAN_T; off <<= 1) {
        int u = (t >= off) ? sh[t - off] : 0;
        __syncthreads();
        sh[t] += u;
        __syncthreads();
    }
    if (i < NN) rowstart[i] = sh[t] - v;      // exclusive
    if (t == SCAN_T - 1) bsums[blockIdx.x] = sh[t];
}

__global__ __launch_bounds__(256) void k_scan2(int* __restrict__ bsums) {
    __shared__ int sh[256];
    int t = threadIdx.x;
    int v = (t < NB0) ? bsums[t] : 0;
    sh[t] = v;
    __syncthreads();
    for (int off = 1; off < 256; off <<= 1) {
        int u = (t >= off) ? sh[t - off] : 0;
        __syncthreads();
        sh[t] += u;
        __syncthreads();
    }
    if (t < NB0) bsums[t] = sh[t] - v;        // exclusive over block sums
}

__global__ __launch_bounds__(SCAN_T) void k_scan3(int* __restrict__ rowstart,
                                                  const int* __restrict__ bsums) {
    int i = blockIdx.x * SCAN_T + threadIdx.x;
    if (i < NN) rowstart[i] += bsums[blockIdx.x];
    if (i == 0) rowstart[NN] = NE;
}

// ---------------- CSR fill (no atomics): slot = rowstart[c] + rank[e] ----------
__global__ void k_fill(const int* __restrict__ row, const int* __restrict__ col,
                       const float* __restrict__ ew, const int* __restrict__ rank,
                       const int* __restrict__ rowstart, int2* __restrict__ csr) {
    int e = blockIdx.x * blockDim.x + threadIdx.x;
    if (e >= NE) return;
    int slot = rowstart[col[e]] + rank[e];
    csr[slot] = make_int2(row[e], __float_as_int(ew[e]));
}

// ---------------- per-node degree: 16 lanes per node, coalesced ---------------
__global__ __launch_bounds__(256) void k_rowdeg(const int2* __restrict__ csr,
                                                const int* __restrict__ rowstart,
                                                float* __restrict__ dis) {
    int t = threadIdx.x;
    int node = blockIdx.x * 16 + (t >> 4);   // NN % 16 == 0
    int f = t & 15;
    int e0 = rowstart[node], e1 = rowstart[node + 1];
    float d = 0.f;
    for (int e = e0 + f; e < e1; e += 16) d += __int_as_float(csr[e].y);
    d += __shfl_xor(d, 1);
    d += __shfl_xor(d, 2);
    d += __shfl_xor(d, 4);
    d += __shfl_xor(d, 8);
    if (f == 0) dis[node] = (d > 0.f) ? (1.0f / sqrtf(d)) : 0.f;
}

// ---------------- csr weight: ew -> dis[src]*ew*dis[dst], coalesced -----------
__global__ __launch_bounds__(256) void k_rownorm(int2* __restrict__ csr,
                                                 const int* __restrict__ rowstart,
                                                 const float* __restrict__ dis) {
    int t = threadIdx.x;
    int node = blockIdx.x * 16 + (t >> 4);
    int f = t & 15;
    int e0 = rowstart[node], e1 = rowstart[node + 1];
    float dc = dis[node];
    for (int e = e0 + f; e < e1; e += 16) {
        int2 p = csr[e];
        float w = dis[p.x] * __int_as_float(p.y) * dc;
        csr[e] = make_int2(p.x, __float_as_int(w));
    }
}

// ---------------- weight split into pre-swizzled MFMA fragments ----------------
// frag layout: [layer][ct:4][kh:2][h:2][lane:64][j:8] bf16
// value: W_l[k = kh*32 + (lane>>4)*8 + j][n = ct*16 + (lane&15)]
__global__ void k_wsplit(const float* __restrict__ conv_w, ushort* __restrict__ wf) {
    int tid = blockIdx.x * blockDim.x + threadIdx.x;   // 4*4*2*64*8 = 16384
    int j = tid & 7;
    int lane = (tid >> 3) & 63;
    int kh = (tid >> 9) & 1;
    int ct = (tid >> 10) & 3;
    int l = tid >> 12;
    int k = kh * 32 + (lane >> 4) * 8 + j;
    int n = ct * 16 + (lane & 15);
    float w = conv_w[l * D * D + k * D + n];
    ushort hi = f2bf(w);
    ushort lo = f2bf(w - bf2f(hi));
    int base = (((l * 4 + ct) * 2 + kh) * 2) * 512 + lane * 8 + j;
    wf[base] = hi;            // h=0
    wf[base + 512] = lo;      // h=1
}

// ---------------- lin0: out = relu(x @ W0 + b0) -> bf16 rows ------------------
__global__ __launch_bounds__(256) void k_lin0(const float* __restrict__ x,
                                              const float* __restrict__ w,
                                              const float* __restrict__ b,
                                              ushort* __restrict__ out) {
    __shared__ float ws[FIN * D];     // 25.6 KB
    __shared__ float xs[16][FIN];     // 6.4 KB
    int t = threadIdx.x;
    for (int i = t; i < FIN * D; i += 256) ws[i] = w[i];
    int r0 = blockIdx.x * 16;
    for (int i = t; i < 16 * FIN; i += 256) {
        int rr = i / FIN, kk = i - rr * FIN;
        xs[rr][kk] = x[(r0 + rr) * FIN + kk];   // NN % 16 == 0
    }
    __syncthreads();
    int wave = t >> 6, lane = t & 63;
    float bv = b[lane];
    for (int ri = wave; ri < 16; ri += 4) {
        float acc = bv;
        #pragma unroll
        for (int k = 0; k < FIN; k += 4) {
            float4 xv = *reinterpret_cast<const float4*>(&xs[ri][k]);
            acc = fmaf(xv.x, ws[(k + 0) * D + lane], acc);
            acc = fmaf(xv.y, ws[(k + 1) * D + lane], acc);
            acc = fmaf(xv.z, ws[(k + 2) * D + lane], acc);
            acc = fmaf(xv.w, ws[(k + 3) * D + lane], acc);
        }
        out[(r0 + ri) * D + lane] = f2bf(fmaxf(acc, 0.f));
    }
}

// ---------------- aggregation: dst[n] = sum_e w_e * src[csr_src[e]]  (bf16 rows)
// 4 nodes per wave, 16 lanes per node; lane owns 4 features.
// Software-pipelined: csr entries for iteration i+1 prefetched during i's gathers,
// so row-gathers never wait on the csr load.
__global__ __launch_bounds__(256, 8) void k_agg(const ushort* __restrict__ src,
                                                const int* __restrict__ rowstart,
                                                const int2* __restrict__ csr,
                                                ushort* __restrict__ dst) {
    int t = threadIdx.x;
    int lane = t & 63;
    int g = lane >> 4;          // node sub-index within wave
    int f = lane & 15;          // feature quad
    int node = blockIdx.x * 16 + (t >> 6) * 4 + g;   // NN % 16 == 0
    int e0 = rowstart[node], e1 = rowstart[node + 1];
    float4 acc = {0.f, 0.f, 0.f, 0.f};
    int2 p0, p1, p2, p3;
    {
        int a0 = e0 + 0 < e1 ? e0 + 0 : 0;
        int a1 = e0 + 1 < e1 ? e0 + 1 : 0;
        int a2 = e0 + 2 < e1 ? e0 + 2 : 0;
        int a3 = e0 + 3 < e1 ? e0 + 3 : 0;
        p0 = csr[a0]; p1 = csr[a1]; p2 = csr[a2]; p3 = csr[a3];
    }
    for (int base = e0; base < e1; base += 4) {
        // prefetch next quad (independent of current gathers)
        int n0 = base + 4 < e1 ? base + 4 : 0;
        int n1 = base + 5 < e1 ? base + 5 : 0;
        int n2 = base + 6 < e1 ? base + 6 : 0;
        int n3 = base + 7 < e1 ? base + 7 : 0;
        int2 q0 = csr[n0], q1 = csr[n1], q2 = csr[n2], q3 = csr[n3];
        // gathers on current quad (csr entries already resident)
        float w0 = (base + 0 < e1) ? __int_as_float(p0.y) : 0.f;
        float w1 = (base + 1 < e1) ? __int_as_float(p1.y) : 0.f;
        float w2 = (base + 2 < e1) ? __int_as_float(p2.y) : 0.f;
        float w3 = (base + 3 < e1) ? __int_as_float(p3.y) : 0.f;
        uint2 v0 = *reinterpret_cast<const uint2*>(&src[p0.x * D + f * 4]);
        uint2 v1 = *reinterpret_cast<const uint2*>(&src[p1.x * D + f * 4]);
        uint2 v2 = *reinterpret_cast<const uint2*>(&src[p2.x * D + f * 4]);
        uint2 v3 = *reinterpret_cast<const uint2*>(&src[p3.x * D + f * 4]);
        acc.x = fmaf(bflo(v0.x), w0, acc.x); acc.y = fmaf(bfhi(v0.x), w0, acc.y);
        acc.z = fmaf(bflo(v0.y), w0, acc.z); acc.w = fmaf(bfhi(v0.y), w0, acc.w);
        acc.x = fmaf(bflo(v1.x), w1, acc.x); acc.y = fmaf(bfhi(v1.x), w1, acc.y);
        acc.z = fmaf(bflo(v1.y), w1, acc.z); acc.w = fmaf(bfhi(v1.y), w1, acc.w);
        acc.x = fmaf(bflo(v2.x), w2, acc.x); acc.y = fmaf(bfhi(v2.x), w2, acc.y);
        acc.z = fmaf(bflo(v2.y), w2, acc.z); acc.w = fmaf(bfhi(v2.y), w2, acc.w);
        acc.x = fmaf(bflo(v3.x), w3, acc.x); acc.y = fmaf(bfhi(v3.x), w3, acc.y);
        acc.z = fmaf(bflo(v3.y), w3, acc.z); acc.w = fmaf(bfhi(v3.y), w3, acc.w);
        p0 = q0; p1 = q1; p2 = q2; p3 = q3;
    }
    uint2 o;
    o.x = (uint)f2bf(acc.x) | ((uint)f2bf(acc.y) << 16);
    o.y = (uint)f2bf(acc.z) | ((uint)f2bf(acc.w) << 16);
    *reinterpret_cast<uint2*>(&dst[node * D + f * 4]) = o;
}

// ---------------- dense via MFMA: out = relu(a @ (Whi+Wlo) + b), bf16 in/out --
__global__ __launch_bounds__(256) void k_mfma_dense(const ushort* __restrict__ a,
                                                    const ushort* __restrict__ wf,
                                                    const float* __restrict__ bias,
                                                    ushort* __restrict__ out) {
    int t = threadIdx.x;
    int wave = t >> 6, lane = t & 63;
    bf16x8 wh[4][2], wl[4][2];
    #pragma unroll
    for (int ct = 0; ct < 4; ++ct)
        #pragma unroll
        for (int kh = 0; kh < 2; ++kh) {
            int base = ((ct * 2 + kh) * 2) * 512 + lane * 8;
            wh[ct][kh] = *reinterpret_cast<const bf16x8*>(&wf[base]);
            wl[ct][kh] = *reinterpret_cast<const bf16x8*>(&wf[base + 512]);
        }
    float bias_v[4];
    #pragma unroll
    for (int ct = 0; ct < 4; ++ct) bias_v[ct] = bias[ct * 16 + (lane & 15)];

    int r = blockIdx.x * 64 + wave * 16;      // 16-row tile (NN % 16 == 0)
    if (r >= NN) return;
    int arow = r + (lane & 15);
    bf16x8 a0 = *reinterpret_cast<const bf16x8*>(&a[arow * D + (lane >> 4) * 8]);
    bf16x8 a1 = *reinterpret_cast<const bf16x8*>(&a[arow * D + 32 + (lane >> 4) * 8]);

    f32x4 acc[4];
    #pragma unroll
    for (int ct = 0; ct < 4; ++ct) {
        acc[ct] = {bias_v[ct], bias_v[ct], bias_v[ct], bias_v[ct]};
        acc[ct] = __builtin_amdgcn_mfma_f32_16x16x32_bf16(a0, wh[ct][0], acc[ct], 0, 0, 0);
        acc[ct] = __builtin_amdgcn_mfma_f32_16x16x32_bf16(a1, wh[ct][1], acc[ct], 0, 0, 0);
        acc[ct] = __builtin_amdgcn_mfma_f32_16x16x32_bf16(a0, wl[ct][0], acc[ct], 0, 0, 0);
        acc[ct] = __builtin_amdgcn_mfma_f32_16x16x32_bf16(a1, wl[ct][1], acc[ct], 0, 0, 0);
    }
    #pragma unroll
    for (int ct = 0; ct < 4; ++ct) {
        int ocol = ct * 16 + (lane & 15);
        #pragma unroll
        for (int i = 0; i < 4; ++i) {
            int orow = r + (lane >> 4) * 4 + i;
            out[orow * D + ocol] = f2bf(fmaxf(acc[ct][i], 0.f));
        }
    }
}

// ---------------- segmented mean-pool over sorted batch (bf16 src) ------------
__global__ __launch_bounds__(256) void k_pool(const ushort* __restrict__ src,
                                              const int* __restrict__ batch,
                                              float* __restrict__ pooled,
                                              float* __restrict__ cnt) {
    int wave = threadIdx.x >> 6, lane = threadIdx.x & 63;
    int n0 = blockIdx.x * 64 + wave * 16;
    float s = 0.f;
    int curg = -1, runlen = 0;
    for (int i = 0; i < 16; ++i) {
        int node = n0 + i;
        if (node >= NN) break;
        int gg = batch[node];
        if (gg != curg) {
            if (curg >= 0) {
                atomicAdd(&pooled[curg * D + lane], s);
                if (lane == 0) atomicAdd(&cnt[curg], (float)runlen);
            }
            curg = gg; s = 0.f; runlen = 0;
        }
        s += bf2f(src[node * D + lane]);
        ++runlen;
    }
    if (curg >= 0) {
        atomicAdd(&pooled[curg * D + lane], s);
        if (lane == 0) atomicAdd(&cnt[curg], (float)runlen);
    }
}

// ---------------- MLP head: one block per graph ----------------
__global__ __launch_bounds__(64) void k_head(const float* __restrict__ pooled,
                                             const float* __restrict__ cnt,
                                             const float* __restrict__ lin1_w,
                                             const float* __restrict__ lin1_b,
                                             const float* __restrict__ fc_w,
                                             const float* __restrict__ fc_b,
                                             const float* __restrict__ lin2_w,
                                             const float* __restrict__ lin2_b,
                                             float* __restrict__ out) {
    __shared__ float buf0[D], buf1[D];
    int g = blockIdx.x, d = threadIdx.x;
    float c = fmaxf(cnt[g], 1.0f);
    buf0[d] = pooled[g * D + d] / c;
    __syncthreads();
    float acc = lin1_b[d];
    #pragma unroll
    for (int k = 0; k < D; ++k) acc += buf0[k] * lin1_w[k * D + d];
    buf1[d] = fmaxf(acc, 0.f);
    __syncthreads();
    acc = fc_b[d];
    #pragma unroll
    for (int k = 0; k < D; ++k) acc += buf1[k] * fc_w[k * D + d];
    buf0[d] = fmaxf(acc, 0.f);
    __syncthreads();
    acc = fc_b[D + d];
    #pragma unroll
    for (int k = 0; k < D; ++k) acc += buf0[k] * fc_w[D * D + k * D + d];
    buf1[d] = fmaxf(acc, 0.f);
    __syncthreads();
    float v = buf1[d] * lin2_w[d];
    #pragma unroll
    for (int off = 32; off; off >>= 1) v += __shfl_down(v, off);
    if (d == 0) out[g] = v + lin2_b[0];
}

extern "C" void kernel_launch(void* const* d_in, const int* in_sizes, int n_in,
                              void* d_out, int out_size, void* d_ws, size_t ws_size,
                              hipStream_t stream) {
    const float* x      = (const float*)d_in[0];
    const int*   ei     = (const int*)  d_in[1];
    const float* ew     = (const float*)d_in[2];
    const int*   batch  = (const int*)  d_in[3];
    const float* lin0_w = (const float*)d_in[4];
    const float* lin0_b = (const float*)d_in[5];
    const float* conv_w = (const float*)d_in[6];
    const float* conv_b = (const float*)d_in[7];
    const float* lin1_w = (const float*)d_in[8];
    const float* lin1_b = (const float*)d_in[9];
    const float* fc_w   = (const float*)d_in[10];
    const float* fc_b   = (const float*)d_in[11];
    const float* lin2_w = (const float*)d_in[12];
    const float* lin2_b = (const float*)d_in[13];
    float* out = (float*)d_out;

    const int* rowv = ei;
    const int* colv = ei + NE;

    // workspace layout (~53 MB)
    ushort* bufA    = (ushort*)d_ws;                  // N*D bf16 (12.8 MB)
    ushort* bufB    = bufA + (size_t)NN * D;          // N*D bf16
    ushort* bufG    = bufB + (size_t)NN * D;          // N*D bf16 (agg scratch)
    int2*   csr     = (int2*)(bufG + (size_t)NN * D); // E (src, weight-bits)
    int*   rowstart = (int*)(csr + NE);               // N+1
    float* dis      = (float*)(rowstart + NN + 1);    // N
    int*   counts   = (int*)(dis + NN);               // N
    int*   bsums    = counts + NN;                    // 256
    float* pooled   = (float*)(bsums + 256);          // G*D
    float* cnt      = pooled + NG * D;                // G
    ushort* wfrags  = (ushort*)(cnt + NG);            // 4*8192 bf16 = 64 KB
    int*   rank     = (int*)bufB;                     // E ints, overlays bufB

    hipMemsetAsync(counts, 0, NN * sizeof(int), stream);
    hipMemsetAsync(pooled, 0, (NG * D + NG) * sizeof(float), stream);

    k_rank<<<(NE + 255) / 256, 256, 0, stream>>>(colv, counts, rank);
    k_scan1<<<NB0, SCAN_T, 0, stream>>>(counts, rowstart, bsums);
    k_scan2<<<1, 256, 0, stream>>>(bsums);
    k_scan3<<<NB0, SCAN_T, 0, stream>>>(rowstart, bsums);
    k_fill<<<(NE + 255) / 256, 256, 0, stream>>>(rowv, colv, ew, rank, rowstart, csr);
    k_rowdeg<<<NN / 16, 256, 0, stream>>>(csr, rowstart, dis);
    k_rownorm<<<NN / 16, 256, 0, stream>>>(csr, rowstart, dis);
    k_wsplit<<<64, 256, 0, stream>>>(conv_w, wfrags);

    k_lin0<<<NN / 16, 256, 0, stream>>>(x, lin0_w, lin0_b, bufA);

    int dg = (NN + 63) / 64;
    // conv1: A -> G -> B
    k_agg<<<NN / 16, 256, 0, stream>>>(bufA, rowstart, csr, bufG);
    k_mfma_dense<<<dg, 256, 0, stream>>>(bufG, wfrags + 0 * 8192, conv_b + 0 * D, bufB);
    // conv2: B -> G -> A
    k_agg<<<NN / 16, 256, 0, stream>>>(bufB, rowstart, csr, bufG);
    k_mfma_dense<<<dg, 256, 0, stream>>>(bufG, wfrags + 1 * 8192, conv_b + 1 * D, bufA);
    // conv3: A -> G -> B
    k_agg<<<NN / 16, 256, 0, stream>>>(bufA, rowstart, csr, bufG);
    k_mfma_dense<<<dg, 256, 0, stream>>>(bufG, wfrags + 2 * 8192, conv_b + 2 * D, bufB);
    // conv4: B -> G -> A
    k_agg<<<NN / 16, 256, 0, stream>>>(bufB, rowstart, csr, bufG);
    k_mfma_dense<<<dg, 256, 0, stream>>>(bufG, wfrags + 3 * 8192, conv_b + 3 * D, bufA);

    k_pool<<<(NN + 63) / 64, 256, 0, stream>>>(bufA, batch, pooled, cnt);
    k_head<<<NG, 64, 0, stream>>>(pooled, cnt, lin1_w, lin1_b, fc_w, fc_b,
                                  lin2_w, lin2_b, out);
}

// Round 9
// 331.060 us; speedup vs baseline: 2.1326x; 1.1663x over previous
//
#include <hip/hip_runtime.h>

#define NN 100000     // nodes
#define NE 1600000    // edges
#define FIN 100
#define D 64
#define NCONV 4
#define NG 500

// ---- bucket-sort CSR build params ----
#define NB 196                          // coarse buckets (col >> 9)
#define BSH 9
#define EPB 2048                        // edges per block in hist/scatter
#define NBLKA ((NE + EPB - 1) / EPB)    // 782
#define NSCAN (NB * NBLKA)              // 153272
#define SB 512                          // scan / bcsr block size
#define NBLKS ((NSCAN + SB - 1) / SB)   // 300

typedef unsigned int uint;
typedef unsigned short ushort;
typedef __attribute__((ext_vector_type(8))) short bf16x8;
typedef __attribute__((ext_vector_type(4))) float f32x4;

// f32 -> bf16 round-to-nearest-even
__device__ inline ushort f2bf(float x) {
    uint u = __float_as_uint(x);
    u += 0x7fffu + ((u >> 16) & 1u);
    return (ushort)(u >> 16);
}
__device__ inline float bflo(uint u) { return __uint_as_float(u << 16); }
__device__ inline float bfhi(uint u) { return __uint_as_float(u & 0xffff0000u); }
__device__ inline float bf2f(ushort s) { return __uint_as_float((uint)s << 16); }

// ---------------- pass A1: per-block LDS histogram over 196 buckets ----------
__global__ __launch_bounds__(256) void k_hist(const int* __restrict__ col,
                                              int* __restrict__ ghist) {
    __shared__ int lh[NB];
    int t = threadIdx.x;
    if (t < NB) lh[t] = 0;
    __syncthreads();
    int base = blockIdx.x * EPB;
    #pragma unroll
    for (int i = 0; i < 8; ++i) {
        int e = base + i * 256 + t;
        if (e < NE) atomicAdd(&lh[col[e] >> BSH], 1);
    }
    __syncthreads();
    if (t < NB) ghist[t * NBLKA + blockIdx.x] = lh[t];
}

// ---------------- generic two-level exclusive scan ----------------
__global__ __launch_bounds__(SB) void s_scan1(const int* __restrict__ in,
                                              int* __restrict__ out,
                                              int* __restrict__ bsums, int n) {
    __shared__ int sh[SB];
    int t = threadIdx.x, i = blockIdx.x * SB + t;
    int v = (i < n) ? in[i] : 0;
    sh[t] = v;
    __syncthreads();
    for (int off = 1; off < SB; off <<= 1) {
        int u = (t >= off) ? sh[t - off] : 0;
        __syncthreads();
        sh[t] += u;
        __syncthreads();
    }
    if (i < n) out[i] = sh[t] - v;
    if (t == SB - 1) bsums[blockIdx.x] = sh[t];
}

__global__ __launch_bounds__(SB) void s_scan2(int* __restrict__ bsums, int nb) {
    __shared__ int sh[SB];
    int t = threadIdx.x;
    int v = (t < nb) ? bsums[t] : 0;
    sh[t] = v;
    __syncthreads();
    for (int off = 1; off < SB; off <<= 1) {
        int u = (t >= off) ? sh[t - off] : 0;
        __syncthreads();
        sh[t] += u;
        __syncthreads();
    }
    if (t < nb) bsums[t] = sh[t] - v;
}

__global__ __launch_bounds__(SB) void s_scan3(int* __restrict__ out,
                                              const int* __restrict__ bsums, int n) {
    int i = blockIdx.x * SB + threadIdx.x;
    if (i < n) out[i] += bsums[blockIdx.x];
}

// ---------------- pass A3: scatter edges into bucket-sorted order -------------
// sorted[pos] = (row | collo<<17, ew_bits); pos from LDS cursor per bucket.
__global__ __launch_bounds__(256) void k_scatter(const int* __restrict__ row,
                                                 const int* __restrict__ col,
                                                 const float* __restrict__ ew,
                                                 const int* __restrict__ gscan,
                                                 int2* __restrict__ sorted) {
    __shared__ int lcur[NB];
    int t = threadIdx.x;
    if (t < NB) lcur[t] = gscan[t * NBLKA + blockIdx.x];
    __syncthreads();
    int base = blockIdx.x * EPB;
    #pragma unroll
    for (int i = 0; i < 8; ++i) {
        int e = base + i * 256 + t;
        if (e < NE) {
            int c = col[e];
            int pos = atomicAdd(&lcur[c >> BSH], 1);
            sorted[pos] = make_int2(row[e] | ((c & 511) << 17), __float_as_int(ew[e]));
        }
    }
}

// ---------------- pass B: per-bucket fine CSR (512 cols, LDS count+scan) ------
__global__ __launch_bounds__(SB) void k_bcsr(const int2* __restrict__ sorted,
                                             const int* __restrict__ gscan,
                                             int* __restrict__ rowstart,
                                             int2* __restrict__ csr) {
    __shared__ int lcnt[SB];
    __shared__ int lscan[SB];
    int t = threadIdx.x, b = blockIdx.x;
    int base = gscan[b * NBLKA];
    int end  = (b == NB - 1) ? NE : gscan[(b + 1) * NBLKA];
    lcnt[t] = 0;
    __syncthreads();
    for (int e = base + t; e < end; e += SB)
        atomicAdd(&lcnt[sorted[e].x >> 17], 1);
    __syncthreads();
    int v = lcnt[t];
    lscan[t] = v;
    __syncthreads();
    for (int off = 1; off < SB; off <<= 1) {
        int u = (t >= off) ? lscan[t - off] : 0;
        __syncthreads();
        lscan[t] += u;
        __syncthreads();
    }
    int ex = lscan[t] - v;           // exclusive scan within bucket
    int idx = b * SB + t;
    if (idx <= NN) rowstart[idx] = base + ex;
    lcnt[t] = base + ex;             // cursor
    __syncthreads();
    for (int e = base + t; e < end; e += SB) {
        int2 p = sorted[e];
        int slot = atomicAdd(&lcnt[p.x >> 17], 1);
        csr[slot] = make_int2(p.x & 0x1FFFF, p.y);
    }
}

// ---------------- per-node degree: 16 lanes per node, coalesced ---------------
__global__ __launch_bounds__(256) void k_rowdeg(const int2* __restrict__ csr,
                                                const int* __restrict__ rowstart,
                                                float* __restrict__ dis) {
    int t = threadIdx.x;
    int node = blockIdx.x * 16 + (t >> 4);   // NN % 16 == 0
    int f = t & 15;
    int e0 = rowstart[node], e1 = rowstart[node + 1];
    float d = 0.f;
    for (int e = e0 + f; e < e1; e += 16) d += __int_as_float(csr[e].y);
    d += __shfl_xor(d, 1);
    d += __shfl_xor(d, 2);
    d += __shfl_xor(d, 4);
    d += __shfl_xor(d, 8);
    if (f == 0) dis[node] = (d > 0.f) ? (1.0f / sqrtf(d)) : 0.f;
}

// ---------------- csr weight: ew -> dis[src]*ew*dis[dst], coalesced -----------
__global__ __launch_bounds__(256) void k_rownorm(int2* __restrict__ csr,
                                                 const int* __restrict__ rowstart,
                                                 const float* __restrict__ dis) {
    int t = threadIdx.x;
    int node = blockIdx.x * 16 + (t >> 4);
    int f = t & 15;
    int e0 = rowstart[node], e1 = rowstart[node + 1];
    float dc = dis[node];
    for (int e = e0 + f; e < e1; e += 16) {
        int2 p = csr[e];
        float w = dis[p.x] * __int_as_float(p.y) * dc;
        csr[e] = make_int2(p.x, __float_as_int(w));
    }
}

// ---------------- weight split into pre-swizzled MFMA fragments ----------------
__global__ void k_wsplit(const float* __restrict__ conv_w, ushort* __restrict__ wf) {
    int tid = blockIdx.x * blockDim.x + threadIdx.x;   // 4*4*2*64*8 = 16384
    int j = tid & 7;
    int lane = (tid >> 3) & 63;
    int kh = (tid >> 9) & 1;
    int ct = (tid >> 10) & 3;
    int l = tid >> 12;
    int k = kh * 32 + (lane >> 4) * 8 + j;
    int n = ct * 16 + (lane & 15);
    float w = conv_w[l * D * D + k * D + n];
    ushort hi = f2bf(w);
    ushort lo = f2bf(w - bf2f(hi));
    int base = (((l * 4 + ct) * 2 + kh) * 2) * 512 + lane * 8 + j;
    wf[base] = hi;            // h=0
    wf[base + 512] = lo;      // h=1
}

// ---------------- lin0: out = relu(x @ W0 + b0) -> bf16 rows ------------------
__global__ __launch_bounds__(256) void k_lin0(const float* __restrict__ x,
                                              const float* __restrict__ w,
                                              const float* __restrict__ b,
                                              ushort* __restrict__ out) {
    __shared__ float ws[FIN * D];     // 25.6 KB
    __shared__ float xs[16][FIN];     // 6.4 KB
    int t = threadIdx.x;
    for (int i = t; i < FIN * D; i += 256) ws[i] = w[i];
    int r0 = blockIdx.x * 16;
    for (int i = t; i < 16 * FIN; i += 256) {
        int rr = i / FIN, kk = i - rr * FIN;
        xs[rr][kk] = x[(r0 + rr) * FIN + kk];   // NN % 16 == 0
    }
    __syncthreads();
    int wave = t >> 6, lane = t & 63;
    float bv = b[lane];
    for (int ri = wave; ri < 16; ri += 4) {
        float acc = bv;
        #pragma unroll
        for (int k = 0; k < FIN; k += 4) {
            float4 xv = *reinterpret_cast<const float4*>(&xs[ri][k]);
            acc = fmaf(xv.x, ws[(k + 0) * D + lane], acc);
            acc = fmaf(xv.y, ws[(k + 1) * D + lane], acc);
            acc = fmaf(xv.z, ws[(k + 2) * D + lane], acc);
            acc = fmaf(xv.w, ws[(k + 3) * D + lane], acc);
        }
        out[(r0 + ri) * D + lane] = f2bf(fmaxf(acc, 0.f));
    }
}

// ---------------- aggregation (software-pipelined CSR gather) -----------------
__global__ __launch_bounds__(256, 8) void k_agg(const ushort* __restrict__ src,
                                                const int* __restrict__ rowstart,
                                                const int2* __restrict__ csr,
                                                ushort* __restrict__ dst) {
    int t = threadIdx.x;
    int lane = t & 63;
    int g = lane >> 4;          // node sub-index within wave
    int f = lane & 15;          // feature quad
    int node = blockIdx.x * 16 + (t >> 6) * 4 + g;   // NN % 16 == 0
    int e0 = rowstart[node], e1 = rowstart[node + 1];
    float4 acc = {0.f, 0.f, 0.f, 0.f};
    int2 p0, p1, p2, p3;
    {
        int a0 = e0 + 0 < e1 ? e0 + 0 : 0;
        int a1 = e0 + 1 < e1 ? e0 + 1 : 0;
        int a2 = e0 + 2 < e1 ? e0 + 2 : 0;
        int a3 = e0 + 3 < e1 ? e0 + 3 : 0;
        p0 = csr[a0]; p1 = csr[a1]; p2 = csr[a2]; p3 = csr[a3];
    }
    for (int base = e0; base < e1; base += 4) {
        int n0 = base + 4 < e1 ? base + 4 : 0;
        int n1 = base + 5 < e1 ? base + 5 : 0;
        int n2 = base + 6 < e1 ? base + 6 : 0;
        int n3 = base + 7 < e1 ? base + 7 : 0;
        int2 q0 = csr[n0], q1 = csr[n1], q2 = csr[n2], q3 = csr[n3];
        float w0 = (base + 0 < e1) ? __int_as_float(p0.y) : 0.f;
        float w1 = (base + 1 < e1) ? __int_as_float(p1.y) : 0.f;
        float w2 = (base + 2 < e1) ? __int_as_float(p2.y) : 0.f;
        float w3 = (base + 3 < e1) ? __int_as_float(p3.y) : 0.f;
        uint2 v0 = *reinterpret_cast<const uint2*>(&src[p0.x * D + f * 4]);
        uint2 v1 = *reinterpret_cast<const uint2*>(&src[p1.x * D + f * 4]);
        uint2 v2 = *reinterpret_cast<const uint2*>(&src[p2.x * D + f * 4]);
        uint2 v3 = *reinterpret_cast<const uint2*>(&src[p3.x * D + f * 4]);
        acc.x = fmaf(bflo(v0.x), w0, acc.x); acc.y = fmaf(bfhi(v0.x), w0, acc.y);
        acc.z = fmaf(bflo(v0.y), w0, acc.z); acc.w = fmaf(bfhi(v0.y), w0, acc.w);
        acc.x = fmaf(bflo(v1.x), w1, acc.x); acc.y = fmaf(bfhi(v1.x), w1, acc.y);
        acc.z = fmaf(bflo(v1.y), w1, acc.z); acc.w = fmaf(bfhi(v1.y), w1, acc.w);
        acc.x = fmaf(bflo(v2.x), w2, acc.x); acc.y = fmaf(bfhi(v2.x), w2, acc.y);
        acc.z = fmaf(bflo(v2.y), w2, acc.z); acc.w = fmaf(bfhi(v2.y), w2, acc.w);
        acc.x = fmaf(bflo(v3.x), w3, acc.x); acc.y = fmaf(bfhi(v3.x), w3, acc.y);
        acc.z = fmaf(bflo(v3.y), w3, acc.z); acc.w = fmaf(bfhi(v3.y), w3, acc.w);
        p0 = q0; p1 = q1; p2 = q2; p3 = q3;
    }
    uint2 o;
    o.x = (uint)f2bf(acc.x) | ((uint)f2bf(acc.y) << 16);
    o.y = (uint)f2bf(acc.z) | ((uint)f2bf(acc.w) << 16);
    *reinterpret_cast<uint2*>(&dst[node * D + f * 4]) = o;
}

// ---------------- dense via MFMA: out = relu(a @ (Whi+Wlo) + b), bf16 in/out --
__global__ __launch_bounds__(256) void k_mfma_dense(const ushort* __restrict__ a,
                                                    const ushort* __restrict__ wf,
                                                    const float* __restrict__ bias,
                                                    ushort* __restrict__ out) {
    int t = threadIdx.x;
    int wave = t >> 6, lane = t & 63;
    bf16x8 wh[4][2], wl[4][2];
    #pragma unroll
    for (int ct = 0; ct < 4; ++ct)
        #pragma unroll
        for (int kh = 0; kh < 2; ++kh) {
            int base = ((ct * 2 + kh) * 2) * 512 + lane * 8;
            wh[ct][kh] = *reinterpret_cast<const bf16x8*>(&wf[base]);
            wl[ct][kh] = *reinterpret_cast<const bf16x8*>(&wf[base + 512]);
        }
    float bias_v[4];
    #pragma unroll
    for (int ct = 0; ct < 4; ++ct) bias_v[ct] = bias[ct * 16 + (lane & 15)];

    int r = blockIdx.x * 64 + wave * 16;      // 16-row tile (NN % 16 == 0)
    if (r >= NN) return;
    int arow = r + (lane & 15);
    bf16x8 a0 = *reinterpret_cast<const bf16x8*>(&a[arow * D + (lane >> 4) * 8]);
    bf16x8 a1 = *reinterpret_cast<const bf16x8*>(&a[arow * D + 32 + (lane >> 4) * 8]);

    f32x4 acc[4];
    #pragma unroll
    for (int ct = 0; ct < 4; ++ct) {
        acc[ct] = {bias_v[ct], bias_v[ct], bias_v[ct], bias_v[ct]};
        acc[ct] = __builtin_amdgcn_mfma_f32_16x16x32_bf16(a0, wh[ct][0], acc[ct], 0, 0, 0);
        acc[ct] = __builtin_amdgcn_mfma_f32_16x16x32_bf16(a1, wh[ct][1], acc[ct], 0, 0, 0);
        acc[ct] = __builtin_amdgcn_mfma_f32_16x16x32_bf16(a0, wl[ct][0], acc[ct], 0, 0, 0);
        acc[ct] = __builtin_amdgcn_mfma_f32_16x16x32_bf16(a1, wl[ct][1], acc[ct], 0, 0, 0);
    }
    #pragma unroll
    for (int ct = 0; ct < 4; ++ct) {
        int ocol = ct * 16 + (lane & 15);
        #pragma unroll
        for (int i = 0; i < 4; ++i) {
            int orow = r + (lane >> 4) * 4 + i;
            out[orow * D + ocol] = f2bf(fmaxf(acc[ct][i], 0.f));
        }
    }
}

// ---------------- segmented mean-pool over sorted batch (bf16 src) ------------
__global__ __launch_bounds__(256) void k_pool(const ushort* __restrict__ src,
                                              const int* __restrict__ batch,
                                              float* __restrict__ pooled,
                                              float* __restrict__ cnt) {
    int wave = threadIdx.x >> 6, lane = threadIdx.x & 63;
    int n0 = blockIdx.x * 64 + wave * 16;
    float s = 0.f;
    int curg = -1, runlen = 0;
    for (int i = 0; i < 16; ++i) {
        int node = n0 + i;
        if (node >= NN) break;
        int gg = batch[node];
        if (gg != curg) {
            if (curg >= 0) {
                atomicAdd(&pooled[curg * D + lane], s);
                if (lane == 0) atomicAdd(&cnt[curg], (float)runlen);
            }
            curg = gg; s = 0.f; runlen = 0;
        }
        s += bf2f(src[node * D + lane]);
        ++runlen;
    }
    if (curg >= 0) {
        atomicAdd(&pooled[curg * D + lane], s);
        if (lane == 0) atomicAdd(&cnt[curg], (float)runlen);
    }
}

// ---------------- MLP head: one block per graph ----------------
__global__ __launch_bounds__(64) void k_head(const float* __restrict__ pooled,
                                             const float* __restrict__ cnt,
                                             const float* __restrict__ lin1_w,
                                             const float* __restrict__ lin1_b,
                                             const float* __restrict__ fc_w,
                                             const float* __restrict__ fc_b,
                                             const float* __restrict__ lin2_w,
                                             const float* __restrict__ lin2_b,
                                             float* __restrict__ out) {
    __shared__ float buf0[D], buf1[D];
    int g = blockIdx.x, d = threadIdx.x;
    float c = fmaxf(cnt[g], 1.0f);
    buf0[d] = pooled[g * D + d] / c;
    __syncthreads();
    float acc = lin1_b[d];
    #pragma unroll
    for (int k = 0; k < D; ++k) acc += buf0[k] * lin1_w[k * D + d];
    buf1[d] = fmaxf(acc, 0.f);
    __syncthreads();
    acc = fc_b[d];
    #pragma unroll
    for (int k = 0; k < D; ++k) acc += buf1[k] * fc_w[k * D + d];
    buf0[d] = fmaxf(acc, 0.f);
    __syncthreads();
    acc = fc_b[D + d];
    #pragma unroll
    for (int k = 0; k < D; ++k) acc += buf0[k] * fc_w[D * D + k * D + d];
    buf1[d] = fmaxf(acc, 0.f);
    __syncthreads();
    float v = buf1[d] * lin2_w[d];
    #pragma unroll
    for (int off = 32; off; off >>= 1) v += __shfl_down(v, off);
    if (d == 0) out[g] = v + lin2_b[0];
}

extern "C" void kernel_launch(void* const* d_in, const int* in_sizes, int n_in,
                              void* d_out, int out_size, void* d_ws, size_t ws_size,
                              hipStream_t stream) {
    const float* x      = (const float*)d_in[0];
    const int*   ei     = (const int*)  d_in[1];
    const float* ew     = (const float*)d_in[2];
    const int*   batch  = (const int*)  d_in[3];
    const float* lin0_w = (const float*)d_in[4];
    const float* lin0_b = (const float*)d_in[5];
    const float* conv_w = (const float*)d_in[6];
    const float* conv_b = (const float*)d_in[7];
    const float* lin1_w = (const float*)d_in[8];
    const float* lin1_b = (const float*)d_in[9];
    const float* fc_w   = (const float*)d_in[10];
    const float* fc_b   = (const float*)d_in[11];
    const float* lin2_w = (const float*)d_in[12];
    const float* lin2_b = (const float*)d_in[13];
    float* out = (float*)d_out;

    const int* rowv = ei;
    const int* colv = ei + NE;

    // workspace layout (~53 MB)
    ushort* bufA    = (ushort*)d_ws;                  // N*D bf16 (12.8 MB)
    ushort* bufB    = bufA + (size_t)NN * D;          // N*D bf16
    ushort* bufG    = bufB + (size_t)NN * D;          // N*D bf16 (agg scratch)
    int2*   csr     = (int2*)(bufG + (size_t)NN * D); // E (src, weight-bits)
    int*   rowstart = (int*)(csr + NE);               // N+1
    float* dis      = (float*)(rowstart + NN + 1);    // N
    float* pooled   = dis + NN;                       // G*D
    float* cnt      = pooled + NG * D;                // G
    ushort* wfrags  = (ushort*)(cnt + NG);            // 4*8192 bf16 = 64 KB
    // build-phase overlays (dead regions during build):
    int2*  sorted   = (int2*)bufG;                    // E * 8B == N*D*2B exactly
    int*   ghist    = (int*)bufB;                     // NSCAN ints (613 KB)
    int*   gscan    = ghist + NSCAN;                  // NSCAN ints
    int*   bsums    = gscan + NSCAN;                  // NBLKS ints

    hipMemsetAsync(pooled, 0, (NG * D + NG) * sizeof(float), stream);

    // ---- atomic-free CSR build (LDS multisplit counting sort) ----
    k_hist<<<NBLKA, 256, 0, stream>>>(colv, ghist);
    s_scan1<<<NBLKS, SB, 0, stream>>>(ghist, gscan, bsums, NSCAN);
    s_scan2<<<1, SB, 0, stream>>>(bsums, NBLKS);
    s_scan3<<<NBLKS, SB, 0, stream>>>(gscan, bsums, NSCAN);
    k_scatter<<<NBLKA, 256, 0, stream>>>(rowv, colv, ew, gscan, sorted);
    k_bcsr<<<NB, SB, 0, stream>>>(sorted, gscan, rowstart, csr);

    k_rowdeg<<<NN / 16, 256, 0, stream>>>(csr, rowstart, dis);
    k_rownorm<<<NN / 16, 256, 0, stream>>>(csr, rowstart, dis);
    k_wsplit<<<64, 256, 0, stream>>>(conv_w, wfrags);

    k_lin0<<<NN / 16, 256, 0, stream>>>(x, lin0_w, lin0_b, bufA);

    int dg = (NN + 63) / 64;
    // conv1: A -> G -> B
    k_agg<<<NN / 16, 256, 0, stream>>>(bufA, rowstart, csr, bufG);
    k_mfma_dense<<<dg, 256, 0, stream>>>(bufG, wfrags + 0 * 8192, conv_b + 0 * D, bufB);
    // conv2: B -> G -> A
    k_agg<<<NN / 16, 256, 0, stream>>>(bufB, rowstart, csr, bufG);
    k_mfma_dense<<<dg, 256, 0, stream>>>(bufG, wfrags + 1 * 8192, conv_b + 1 * D, bufA);
    // conv3: A -> G -> B
    k_agg<<<NN / 16, 256, 0, stream>>>(bufA, rowstart, csr, bufG);
    k_mfma_dense<<<dg, 256, 0, stream>>>(bufG, wfrags + 2 * 8192, conv_b + 2 * D, bufB);
    // conv4: B -> G -> A
    k_agg<<<NN / 16, 256, 0, stream>>>(bufB, rowstart, csr, bufG);
    k_mfma_dense<<<dg, 256, 0, stream>>>(bufG, wfrags + 3 * 8192, conv_b + 3 * D, bufA);

    k_pool<<<(NN + 63) / 64, 256, 0, stream>>>(bufA, batch, pooled, cnt);
    k_head<<<NG, 64, 0, stream>>>(pooled, cnt, lin1_w, lin1_b, fc_w, fc_b,
                                  lin2_w, lin2_b, out);
}

// Round 10
// 302.901 us; speedup vs baseline: 2.3308x; 1.0930x over previous
//
#include <hip/hip_runtime.h>

#define NN 100000     // nodes
#define NE 1600000    // edges
#define FIN 100
#define D 64
#define NCONV 4
#define NG 500

// ---- bucket-sort CSR build params ----
#define NB 196                          // coarse buckets (col >> 9)
#define BSH 9
#define EPB 2048                        // edges per block in hist/scatter
#define NBLKA ((NE + EPB - 1) / EPB)    // 782
#define NSCAN (NB * NBLKA)              // 153272
#define SB 512                          // scan / bcsr block size
#define NBLKS ((NSCAN + SB - 1) / SB)   // 300

#define LSTR 136                        // LDS row stride (bf16) for lin0 staging

typedef unsigned int uint;
typedef unsigned short ushort;
typedef __attribute__((ext_vector_type(8))) short bf16x8;
typedef __attribute__((ext_vector_type(4))) float f32x4;

// f32 -> bf16 round-to-nearest-even
__device__ inline ushort f2bf(float x) {
    uint u = __float_as_uint(x);
    u += 0x7fffu + ((u >> 16) & 1u);
    return (ushort)(u >> 16);
}
__device__ inline float bflo(uint u) { return __uint_as_float(u << 16); }
__device__ inline float bfhi(uint u) { return __uint_as_float(u & 0xffff0000u); }
__device__ inline float bf2f(ushort s) { return __uint_as_float((uint)s << 16); }

// ---------------- pass A1: per-block LDS histogram over 196 buckets ----------
__global__ __launch_bounds__(256) void k_hist(const int* __restrict__ col,
                                              int* __restrict__ ghist) {
    __shared__ int lh[NB];
    int t = threadIdx.x;
    if (t < NB) lh[t] = 0;
    __syncthreads();
    int base = blockIdx.x * EPB;
    #pragma unroll
    for (int i = 0; i < 8; ++i) {
        int e = base + i * 256 + t;
        if (e < NE) atomicAdd(&lh[col[e] >> BSH], 1);
    }
    __syncthreads();
    if (t < NB) ghist[t * NBLKA + blockIdx.x] = lh[t];
}

// ---------------- generic two-level exclusive scan ----------------
__global__ __launch_bounds__(SB) void s_scan1(const int* __restrict__ in,
                                              int* __restrict__ out,
                                              int* __restrict__ bsums, int n) {
    __shared__ int sh[SB];
    int t = threadIdx.x, i = blockIdx.x * SB + t;
    int v = (i < n) ? in[i] : 0;
    sh[t] = v;
    __syncthreads();
    for (int off = 1; off < SB; off <<= 1) {
        int u = (t >= off) ? sh[t - off] : 0;
        __syncthreads();
        sh[t] += u;
        __syncthreads();
    }
    if (i < n) out[i] = sh[t] - v;
    if (t == SB - 1) bsums[blockIdx.x] = sh[t];
}

__global__ __launch_bounds__(SB) void s_scan2(int* __restrict__ bsums, int nb) {
    __shared__ int sh[SB];
    int t = threadIdx.x;
    int v = (t < nb) ? bsums[t] : 0;
    sh[t] = v;
    __syncthreads();
    for (int off = 1; off < SB; off <<= 1) {
        int u = (t >= off) ? sh[t - off] : 0;
        __syncthreads();
        sh[t] += u;
        __syncthreads();
    }
    if (t < nb) bsums[t] = sh[t] - v;
}

__global__ __launch_bounds__(SB) void s_scan3(int* __restrict__ out,
                                              const int* __restrict__ bsums, int n) {
    int i = blockIdx.x * SB + threadIdx.x;
    if (i < n) out[i] += bsums[blockIdx.x];
}

// ---------------- pass A3: scatter edges into bucket-sorted order -------------
__global__ __launch_bounds__(256) void k_scatter(const int* __restrict__ row,
                                                 const int* __restrict__ col,
                                                 const float* __restrict__ ew,
                                                 const int* __restrict__ gscan,
                                                 int2* __restrict__ sorted) {
    __shared__ int lcur[NB];
    int t = threadIdx.x;
    if (t < NB) lcur[t] = gscan[t * NBLKA + blockIdx.x];
    __syncthreads();
    int base = blockIdx.x * EPB;
    #pragma unroll
    for (int i = 0; i < 8; ++i) {
        int e = base + i * 256 + t;
        if (e < NE) {
            int c = col[e];
            int pos = atomicAdd(&lcur[c >> BSH], 1);
            sorted[pos] = make_int2(row[e] | ((c & 511) << 17), __float_as_int(ew[e]));
        }
    }
}

// ---------------- pass B: per-bucket fine CSR (512 cols, LDS count+scan) ------
__global__ __launch_bounds__(SB) void k_bcsr(const int2* __restrict__ sorted,
                                             const int* __restrict__ gscan,
                                             int* __restrict__ rowstart,
                                             int2* __restrict__ csr) {
    __shared__ int lcnt[SB];
    __shared__ int lscan[SB];
    int t = threadIdx.x, b = blockIdx.x;
    int base = gscan[b * NBLKA];
    int end  = (b == NB - 1) ? NE : gscan[(b + 1) * NBLKA];
    lcnt[t] = 0;
    __syncthreads();
    for (int e = base + t; e < end; e += SB)
        atomicAdd(&lcnt[sorted[e].x >> 17], 1);
    __syncthreads();
    int v = lcnt[t];
    lscan[t] = v;
    __syncthreads();
    for (int off = 1; off < SB; off <<= 1) {
        int u = (t >= off) ? lscan[t - off] : 0;
        __syncthreads();
        lscan[t] += u;
        __syncthreads();
    }
    int ex = lscan[t] - v;           // exclusive scan within bucket
    int idx = b * SB + t;
    if (idx <= NN) rowstart[idx] = base + ex;
    lcnt[t] = base + ex;             // cursor
    __syncthreads();
    for (int e = base + t; e < end; e += SB) {
        int2 p = sorted[e];
        int slot = atomicAdd(&lcnt[p.x >> 17], 1);
        csr[slot] = make_int2(p.x & 0x1FFFF, p.y);
    }
}

// ---------------- per-node degree: 16 lanes per node, coalesced ---------------
__global__ __launch_bounds__(256) void k_rowdeg(const int2* __restrict__ csr,
                                                const int* __restrict__ rowstart,
                                                float* __restrict__ dis) {
    int t = threadIdx.x;
    int node = blockIdx.x * 16 + (t >> 4);   // NN % 16 == 0
    int f = t & 15;
    int e0 = rowstart[node], e1 = rowstart[node + 1];
    float d = 0.f;
    for (int e = e0 + f; e < e1; e += 16) d += __int_as_float(csr[e].y);
    d += __shfl_xor(d, 1);
    d += __shfl_xor(d, 2);
    d += __shfl_xor(d, 4);
    d += __shfl_xor(d, 8);
    if (f == 0) dis[node] = (d > 0.f) ? (1.0f / sqrtf(d)) : 0.f;
}

// ---------------- csr weight: ew -> dis[src]*ew*dis[dst], coalesced -----------
__global__ __launch_bounds__(256) void k_rownorm(int2* __restrict__ csr,
                                                 const int* __restrict__ rowstart,
                                                 const float* __restrict__ dis) {
    int t = threadIdx.x;
    int node = blockIdx.x * 16 + (t >> 4);
    int f = t & 15;
    int e0 = rowstart[node], e1 = rowstart[node + 1];
    float dc = dis[node];
    for (int e = e0 + f; e < e1; e += 16) {
        int2 p = csr[e];
        float w = dis[p.x] * __int_as_float(p.y) * dc;
        csr[e] = make_int2(p.x, __float_as_int(w));
    }
}

// ---------------- conv weight split into pre-swizzled MFMA fragments ----------
// frag layout: [layer][ct:4][kh:2][h:2][lane:64][j:8] bf16
__global__ void k_wsplit(const float* __restrict__ conv_w, ushort* __restrict__ wf) {
    int tid = blockIdx.x * blockDim.x + threadIdx.x;   // 4*4*2*64*8 = 16384
    int j = tid & 7;
    int lane = (tid >> 3) & 63;
    int kh = (tid >> 9) & 1;
    int ct = (tid >> 10) & 3;
    int l = tid >> 12;
    int k = kh * 32 + (lane >> 4) * 8 + j;
    int n = ct * 16 + (lane & 15);
    float w = conv_w[l * D * D + k * D + n];
    ushort hi = f2bf(w);
    ushort lo = f2bf(w - bf2f(hi));
    int base = (((l * 4 + ct) * 2 + kh) * 2) * 512 + lane * 8 + j;
    wf[base] = hi;            // h=0
    wf[base + 512] = lo;      // h=1
}

// ---------------- lin0 weight split: [ct:4][ks:4][h:2][lane:64][j:8], K pad 128
__global__ void k_wsplit0(const float* __restrict__ w, ushort* __restrict__ wf) {
    int tid = blockIdx.x * blockDim.x + threadIdx.x;   // 4*4*64*8 = 8192
    int j = tid & 7;
    int lane = (tid >> 3) & 63;
    int ks = (tid >> 9) & 3;
    int ct = tid >> 11;
    int k = ks * 32 + (lane >> 4) * 8 + j;
    int n = ct * 16 + (lane & 15);
    float v = (k < FIN) ? w[k * D + n] : 0.f;
    ushort hi = f2bf(v);
    ushort lo = f2bf(v - bf2f(hi));
    int base = ((ct * 4 + ks) * 2) * 512 + lane * 8 + j;
    wf[base] = hi;
    wf[base + 512] = lo;
}

// ---------------- lin0 via MFMA: out = relu(x @ W0 + b0) -> bf16 rows ---------
// 64 rows/block (4 waves x 16-row tile). x f32 staged to LDS as bf16 hi/lo
// (K padded 100->128); out = xhi@Whi + xhi@Wlo + xlo@Whi (lo*lo dropped).
__global__ __launch_bounds__(256) void k_lin0_mfma(const float* __restrict__ x,
                                                   const ushort* __restrict__ wf,
                                                   const float* __restrict__ b,
                                                   ushort* __restrict__ out) {
    __shared__ ushort xhi[64 * LSTR];   // 17.4 KB
    __shared__ ushort xlo[64 * LSTR];   // 17.4 KB
    int t = threadIdx.x;
    int r0 = blockIdx.x * 64;
    for (int i = t; i < 1600; i += 256) {           // 64 rows x 25 float4
        int r = i / 25, c4 = i - (i / 25) * 25;
        float4 v = {0.f, 0.f, 0.f, 0.f};
        if (r0 + r < NN)
            v = *reinterpret_cast<const float4*>(&x[(size_t)(r0 + r) * FIN + c4 * 4]);
        int base = r * LSTR + c4 * 4;
        ushort h;
        h = f2bf(v.x); xhi[base + 0] = h; xlo[base + 0] = f2bf(v.x - bf2f(h));
        h = f2bf(v.y); xhi[base + 1] = h; xlo[base + 1] = f2bf(v.y - bf2f(h));
        h = f2bf(v.z); xhi[base + 2] = h; xlo[base + 2] = f2bf(v.z - bf2f(h));
        h = f2bf(v.w); xhi[base + 3] = h; xlo[base + 3] = f2bf(v.w - bf2f(h));
    }
    for (int i = t; i < 64 * 28; i += 256) {        // zero-pad k = 100..127
        int r = i / 28, c = FIN + (i - (i / 28) * 28);
        xhi[r * LSTR + c] = 0;
        xlo[r * LSTR + c] = 0;
    }
    __syncthreads();
    int wave = t >> 6, lane = t & 63;
    int lrow = wave * 16 + (lane & 15);
    bf16x8 ahi[4], alo[4];
    #pragma unroll
    for (int ks = 0; ks < 4; ++ks) {
        int off = lrow * LSTR + ks * 32 + (lane >> 4) * 8;
        ahi[ks] = *reinterpret_cast<const bf16x8*>(&xhi[off]);
        alo[ks] = *reinterpret_cast<const bf16x8*>(&xlo[off]);
    }
    float bv[4];
    #pragma unroll
    for (int ct = 0; ct < 4; ++ct) bv[ct] = b[ct * 16 + (lane & 15)];
    int r = r0 + wave * 16;
    f32x4 acc[4];
    #pragma unroll
    for (int ct = 0; ct < 4; ++ct) {
        acc[ct] = {bv[ct], bv[ct], bv[ct], bv[ct]};
        #pragma unroll
        for (int ks = 0; ks < 4; ++ks) {
            int base = ((ct * 4 + ks) * 2) * 512 + lane * 8;
            bf16x8 wh = *reinterpret_cast<const bf16x8*>(&wf[base]);
            bf16x8 wl = *reinterpret_cast<const bf16x8*>(&wf[base + 512]);
            acc[ct] = __builtin_amdgcn_mfma_f32_16x16x32_bf16(ahi[ks], wh, acc[ct], 0, 0, 0);
            acc[ct] = __builtin_amdgcn_mfma_f32_16x16x32_bf16(ahi[ks], wl, acc[ct], 0, 0, 0);
            acc[ct] = __builtin_amdgcn_mfma_f32_16x16x32_bf16(alo[ks], wh, acc[ct], 0, 0, 0);
        }
    }
    #pragma unroll
    for (int ct = 0; ct < 4; ++ct) {
        int ocol = ct * 16 + (lane & 15);
        #pragma unroll
        for (int i = 0; i < 4; ++i) {
            int orow = r + (lane >> 4) * 4 + i;
            if (orow < NN) out[orow * D + ocol] = f2bf(fmaxf(acc[ct][i], 0.f));
        }
    }
}

// ---------------- aggregation (software-pipelined CSR gather) -----------------
__global__ __launch_bounds__(256, 8) void k_agg(const ushort* __restrict__ src,
                                                const int* __restrict__ rowstart,
                                                const int2* __restrict__ csr,
                                                ushort* __restrict__ dst) {
    int t = threadIdx.x;
    int lane = t & 63;
    int g = lane >> 4;          // node sub-index within wave
    int f = lane & 15;          // feature quad
    int node = blockIdx.x * 16 + (t >> 6) * 4 + g;   // NN % 16 == 0
    int e0 = rowstart[node], e1 = rowstart[node + 1];
    float4 acc = {0.f, 0.f, 0.f, 0.f};
    int2 p0, p1, p2, p3;
    {
        int a0 = e0 + 0 < e1 ? e0 + 0 : 0;
        int a1 = e0 + 1 < e1 ? e0 + 1 : 0;
        int a2 = e0 + 2 < e1 ? e0 + 2 : 0;
        int a3 = e0 + 3 < e1 ? e0 + 3 : 0;
        p0 = csr[a0]; p1 = csr[a1]; p2 = csr[a2]; p3 = csr[a3];
    }
    for (int base = e0; base < e1; base += 4) {
        int n0 = base + 4 < e1 ? base + 4 : 0;
        int n1 = base + 5 < e1 ? base + 5 : 0;
        int n2 = base + 6 < e1 ? base + 6 : 0;
        int n3 = base + 7 < e1 ? base + 7 : 0;
        int2 q0 = csr[n0], q1 = csr[n1], q2 = csr[n2], q3 = csr[n3];
        float w0 = (base + 0 < e1) ? __int_as_float(p0.y) : 0.f;
        float w1 = (base + 1 < e1) ? __int_as_float(p1.y) : 0.f;
        float w2 = (base + 2 < e1) ? __int_as_float(p2.y) : 0.f;
        float w3 = (base + 3 < e1) ? __int_as_float(p3.y) : 0.f;
        uint2 v0 = *reinterpret_cast<const uint2*>(&src[p0.x * D + f * 4]);
        uint2 v1 = *reinterpret_cast<const uint2*>(&src[p1.x * D + f * 4]);
        uint2 v2 = *reinterpret_cast<const uint2*>(&src[p2.x * D + f * 4]);
        uint2 v3 = *reinterpret_cast<const uint2*>(&src[p3.x * D + f * 4]);
        acc.x = fmaf(bflo(v0.x), w0, acc.x); acc.y = fmaf(bfhi(v0.x), w0, acc.y);
        acc.z = fmaf(bflo(v0.y), w0, acc.z); acc.w = fmaf(bfhi(v0.y), w0, acc.w);
        acc.x = fmaf(bflo(v1.x), w1, acc.x); acc.y = fmaf(bfhi(v1.x), w1, acc.y);
        acc.z = fmaf(bflo(v1.y), w1, acc.z); acc.w = fmaf(bfhi(v1.y), w1, acc.w);
        acc.x = fmaf(bflo(v2.x), w2, acc.x); acc.y = fmaf(bfhi(v2.x), w2, acc.y);
        acc.z = fmaf(bflo(v2.y), w2, acc.z); acc.w = fmaf(bfhi(v2.y), w2, acc.w);
        acc.x = fmaf(bflo(v3.x), w3, acc.x); acc.y = fmaf(bfhi(v3.x), w3, acc.y);
        acc.z = fmaf(bflo(v3.y), w3, acc.z); acc.w = fmaf(bfhi(v3.y), w3, acc.w);
        p0 = q0; p1 = q1; p2 = q2; p3 = q3;
    }
    uint2 o;
    o.x = (uint)f2bf(acc.x) | ((uint)f2bf(acc.y) << 16);
    o.y = (uint)f2bf(acc.z) | ((uint)f2bf(acc.w) << 16);
    *reinterpret_cast<uint2*>(&dst[node * D + f * 4]) = o;
}

// ---------------- dense via MFMA: out = relu(a @ (Whi+Wlo) + b), bf16 in/out --
__global__ __launch_bounds__(256) void k_mfma_dense(const ushort* __restrict__ a,
                                                    const ushort* __restrict__ wf,
                                                    const float* __restrict__ bias,
                                                    ushort* __restrict__ out) {
    int t = threadIdx.x;
    int wave = t >> 6, lane = t & 63;
    bf16x8 wh[4][2], wl[4][2];
    #pragma unroll
    for (int ct = 0; ct < 4; ++ct)
        #pragma unroll
        for (int kh = 0; kh < 2; ++kh) {
            int base = ((ct * 2 + kh) * 2) * 512 + lane * 8;
            wh[ct][kh] = *reinterpret_cast<const bf16x8*>(&wf[base]);
            wl[ct][kh] = *reinterpret_cast<const bf16x8*>(&wf[base + 512]);
        }
    float bias_v[4];
    #pragma unroll
    for (int ct = 0; ct < 4; ++ct) bias_v[ct] = bias[ct * 16 + (lane & 15)];

    int r = blockIdx.x * 64 + wave * 16;      // 16-row tile (NN % 16 == 0)
    if (r >= NN) return;
    int arow = r + (lane & 15);
    bf16x8 a0 = *reinterpret_cast<const bf16x8*>(&a[arow * D + (lane >> 4) * 8]);
    bf16x8 a1 = *reinterpret_cast<const bf16x8*>(&a[arow * D + 32 + (lane >> 4) * 8]);

    f32x4 acc[4];
    #pragma unroll
    for (int ct = 0; ct < 4; ++ct) {
        acc[ct] = {bias_v[ct], bias_v[ct], bias_v[ct], bias_v[ct]};
        acc[ct] = __builtin_amdgcn_mfma_f32_16x16x32_bf16(a0, wh[ct][0], acc[ct], 0, 0, 0);
        acc[ct] = __builtin_amdgcn_mfma_f32_16x16x32_bf16(a1, wh[ct][1], acc[ct], 0, 0, 0);
        acc[ct] = __builtin_amdgcn_mfma_f32_16x16x32_bf16(a0, wl[ct][0], acc[ct], 0, 0, 0);
        acc[ct] = __builtin_amdgcn_mfma_f32_16x16x32_bf16(a1, wl[ct][1], acc[ct], 0, 0, 0);
    }
    #pragma unroll
    for (int ct = 0; ct < 4; ++ct) {
        int ocol = ct * 16 + (lane & 15);
        #pragma unroll
        for (int i = 0; i < 4; ++i) {
            int orow = r + (lane >> 4) * 4 + i;
            out[orow * D + ocol] = f2bf(fmaxf(acc[ct][i], 0.f));
        }
    }
}

// ---------------- segmented mean-pool over sorted batch (bf16 src) ------------
__global__ __launch_bounds__(256) void k_pool(const ushort* __restrict__ src,
                                              const int* __restrict__ batch,
                                              float* __restrict__ pooled,
                                              float* __restrict__ cnt) {
    int wave = threadIdx.x >> 6, lane = threadIdx.x & 63;
    int n0 = blockIdx.x * 64 + wave * 16;
    float s = 0.f;
    int curg = -1, runlen = 0;
    for (int i = 0; i < 16; ++i) {
        int node = n0 + i;
        if (node >= NN) break;
        int gg = batch[node];
        if (gg != curg) {
            if (curg >= 0) {
                atomicAdd(&pooled[curg * D + lane], s);
                if (lane == 0) atomicAdd(&cnt[curg], (float)runlen);
            }
            curg = gg; s = 0.f; runlen = 0;
        }
        s += bf2f(src[node * D + lane]);
        ++runlen;
    }
    if (curg >= 0) {
        atomicAdd(&pooled[curg * D + lane], s);
        if (lane == 0) atomicAdd(&cnt[curg], (float)runlen);
    }
}

// ---------------- MLP head: one block per graph ----------------
__global__ __launch_bounds__(64) void k_head(const float* __restrict__ pooled,
                                             const float* __restrict__ cnt,
                                             const float* __restrict__ lin1_w,
                                             const float* __restrict__ lin1_b,
                                             const float* __restrict__ fc_w,
                                             const float* __restrict__ fc_b,
                                             const float* __restrict__ lin2_w,
                                             const float* __restrict__ lin2_b,
                                             float* __restrict__ out) {
    __shared__ float buf0[D], buf1[D];
    int g = blockIdx.x, d = threadIdx.x;
    float c = fmaxf(cnt[g], 1.0f);
    buf0[d] = pooled[g * D + d] / c;
    __syncthreads();
    float acc = lin1_b[d];
    #pragma unroll
    for (int k = 0; k < D; ++k) acc += buf0[k] * lin1_w[k * D + d];
    buf1[d] = fmaxf(acc, 0.f);
    __syncthreads();
    acc = fc_b[d];
    #pragma unroll
    for (int k = 0; k < D; ++k) acc += buf1[k] * fc_w[k * D + d];
    buf0[d] = fmaxf(acc, 0.f);
    __syncthreads();
    acc = fc_b[D + d];
    #pragma unroll
    for (int k = 0; k < D; ++k) acc += buf0[k] * fc_w[D * D + k * D + d];
    buf1[d] = fmaxf(acc, 0.f);
    __syncthreads();
    float v = buf1[d] * lin2_w[d];
    #pragma unroll
    for (int off = 32; off; off >>= 1) v += __shfl_down(v, off);
    if (d == 0) out[g] = v + lin2_b[0];
}

extern "C" void kernel_launch(void* const* d_in, const int* in_sizes, int n_in,
                              void* d_out, int out_size, void* d_ws, size_t ws_size,
                              hipStream_t stream) {
    const float* x      = (const float*)d_in[0];
    const int*   ei     = (const int*)  d_in[1];
    const float* ew     = (const float*)d_in[2];
    const int*   batch  = (const int*)  d_in[3];
    const float* lin0_w = (const float*)d_in[4];
    const float* lin0_b = (const float*)d_in[5];
    const float* conv_w = (const float*)d_in[6];
    const float* conv_b = (const float*)d_in[7];
    const float* lin1_w = (const float*)d_in[8];
    const float* lin1_b = (const float*)d_in[9];
    const float* fc_w   = (const float*)d_in[10];
    const float* fc_b   = (const float*)d_in[11];
    const float* lin2_w = (const float*)d_in[12];
    const float* lin2_b = (const float*)d_in[13];
    float* out = (float*)d_out;

    const int* rowv = ei;
    const int* colv = ei + NE;

    // workspace layout (~53 MB)
    ushort* bufA    = (ushort*)d_ws;                  // N*D bf16 (12.8 MB)
    ushort* bufB    = bufA + (size_t)NN * D;          // N*D bf16
    ushort* bufG    = bufB + (size_t)NN * D;          // N*D bf16 (agg scratch)
    int2*   csr     = (int2*)(bufG + (size_t)NN * D); // E (src, weight-bits)
    int*   rowstart = (int*)(csr + NE);               // N+1
    float* dis      = (float*)(rowstart + NN + 1);    // N
    float* pooled   = dis + NN;                       // G*D
    float* cnt      = pooled + NG * D;                // G
    ushort* wfrags  = (ushort*)(cnt + NG);            // 4*8192 bf16 = 64 KB
    ushort* wfrags0 = wfrags + 4 * 8192;              // 8192*2 bf16 = 32 KB
    // build-phase overlays (dead regions during build):
    int2*  sorted   = (int2*)bufG;                    // E * 8B == N*D*2B exactly
    int*   ghist    = (int*)bufB;                     // NSCAN ints (613 KB)
    int*   gscan    = ghist + NSCAN;                  // NSCAN ints
    int*   bsums    = gscan + NSCAN;                  // NBLKS ints

    hipMemsetAsync(pooled, 0, (NG * D + NG) * sizeof(float), stream);

    // ---- atomic-free CSR build (LDS multisplit counting sort) ----
    k_hist<<<NBLKA, 256, 0, stream>>>(colv, ghist);
    s_scan1<<<NBLKS, SB, 0, stream>>>(ghist, gscan, bsums, NSCAN);
    s_scan2<<<1, SB, 0, stream>>>(bsums, NBLKS);
    s_scan3<<<NBLKS, SB, 0, stream>>>(gscan, bsums, NSCAN);
    k_scatter<<<NBLKA, 256, 0, stream>>>(rowv, colv, ew, gscan, sorted);
    k_bcsr<<<NB, SB, 0, stream>>>(sorted, gscan, rowstart, csr);

    k_rowdeg<<<NN / 16, 256, 0, stream>>>(csr, rowstart, dis);
    k_rownorm<<<NN / 16, 256, 0, stream>>>(csr, rowstart, dis);
    k_wsplit<<<64, 256, 0, stream>>>(conv_w, wfrags);
    k_wsplit0<<<32, 256, 0, stream>>>(lin0_w, wfrags0);

    k_lin0_mfma<<<(NN + 63) / 64, 256, 0, stream>>>(x, wfrags0, lin0_b, bufA);

    int dg = (NN + 63) / 64;
    // conv1: A -> G -> B
    k_agg<<<NN / 16, 256, 0, stream>>>(bufA, rowstart, csr, bufG);
    k_mfma_dense<<<dg, 256, 0, stream>>>(bufG, wfrags + 0 * 8192, conv_b + 0 * D, bufB);
    // conv2: B -> G -> A
    k_agg<<<NN / 16, 256, 0, stream>>>(bufB, rowstart, csr, bufG);
    k_mfma_dense<<<dg, 256, 0, stream>>>(bufG, wfrags + 1 * 8192, conv_b + 1 * D, bufA);
    // conv3: A -> G -> B
    k_agg<<<NN / 16, 256, 0, stream>>>(bufA, rowstart, csr, bufG);
    k_mfma_dense<<<dg, 256, 0, stream>>>(bufG, wfrags + 2 * 8192, conv_b + 2 * D, bufB);
    // conv4: B -> G -> A
    k_agg<<<NN / 16, 256, 0, stream>>>(bufB, rowstart, csr, bufG);
    k_mfma_dense<<<dg, 256, 0, stream>>>(bufG, wfrags + 3 * 8192, conv_b + 3 * D, bufA);

    k_pool<<<(NN + 63) / 64, 256, 0, stream>>>(bufA, batch, pooled, cnt);
    k_head<<<NG, 64, 0, stream>>>(pooled, cnt, lin1_w, lin1_b, fc_w, fc_b,
                                  lin2_w, lin2_b, out);
}

// Round 11
// 280.148 us; speedup vs baseline: 2.5201x; 1.0812x over previous
//
#include <hip/hip_runtime.h>

#define NN 100000     // nodes
#define NE 1600000    // edges
#define FIN 100
#define D 64
#define NCONV 4
#define NG 500

// ---- bucket-sort CSR build params ----
#define NB 196                          // coarse buckets (col >> 9)
#define BSH 9
#define EPB 2048                        // edges per block in hist/scatter
#define NBLKA ((NE + EPB - 1) / EPB)    // 782
#define NSCAN (NB * NBLKA)              // 153272
#define SB 512                          // scan / bcsr block size
#define NBLKS ((NSCAN + SB - 1) / SB)   // 300

#define LSTR 136                        // LDS row stride (bf16) for lin0 staging
#define ASTR 72                         // LDS row stride (ushort) for fused conv tile

typedef unsigned int uint;
typedef unsigned short ushort;
typedef __attribute__((ext_vector_type(8))) short bf16x8;
typedef __attribute__((ext_vector_type(4))) float f32x4;

// f32 -> bf16 round-to-nearest-even
__device__ inline ushort f2bf(float x) {
    uint u = __float_as_uint(x);
    u += 0x7fffu + ((u >> 16) & 1u);
    return (ushort)(u >> 16);
}
__device__ inline float bflo(uint u) { return __uint_as_float(u << 16); }
__device__ inline float bfhi(uint u) { return __uint_as_float(u & 0xffff0000u); }
__device__ inline float bf2f(ushort s) { return __uint_as_float((uint)s << 16); }

// ---------------- pass A1: per-block LDS histogram over 196 buckets ----------
__global__ __launch_bounds__(256) void k_hist(const int* __restrict__ col,
                                              int* __restrict__ ghist) {
    __shared__ int lh[NB];
    int t = threadIdx.x;
    if (t < NB) lh[t] = 0;
    __syncthreads();
    int base = blockIdx.x * EPB;
    #pragma unroll
    for (int i = 0; i < 8; ++i) {
        int e = base + i * 256 + t;
        if (e < NE) atomicAdd(&lh[col[e] >> BSH], 1);
    }
    __syncthreads();
    if (t < NB) ghist[t * NBLKA + blockIdx.x] = lh[t];
}

// ---------------- generic two-level exclusive scan ----------------
__global__ __launch_bounds__(SB) void s_scan1(const int* __restrict__ in,
                                              int* __restrict__ out,
                                              int* __restrict__ bsums, int n) {
    __shared__ int sh[SB];
    int t = threadIdx.x, i = blockIdx.x * SB + t;
    int v = (i < n) ? in[i] : 0;
    sh[t] = v;
    __syncthreads();
    for (int off = 1; off < SB; off <<= 1) {
        int u = (t >= off) ? sh[t - off] : 0;
        __syncthreads();
        sh[t] += u;
        __syncthreads();
    }
    if (i < n) out[i] = sh[t] - v;
    if (t == SB - 1) bsums[blockIdx.x] = sh[t];
}

__global__ __launch_bounds__(SB) void s_scan2(int* __restrict__ bsums, int nb) {
    __shared__ int sh[SB];
    int t = threadIdx.x;
    int v = (t < nb) ? bsums[t] : 0;
    sh[t] = v;
    __syncthreads();
    for (int off = 1; off < SB; off <<= 1) {
        int u = (t >= off) ? sh[t - off] : 0;
        __syncthreads();
        sh[t] += u;
        __syncthreads();
    }
    if (t < nb) bsums[t] = sh[t] - v;
}

__global__ __launch_bounds__(SB) void s_scan3(int* __restrict__ out,
                                              const int* __restrict__ bsums, int n) {
    int i = blockIdx.x * SB + threadIdx.x;
    if (i < n) out[i] += bsums[blockIdx.x];
}

// ---------------- pass A3: scatter edges into bucket-sorted order -------------
__global__ __launch_bounds__(256) void k_scatter(const int* __restrict__ row,
                                                 const int* __restrict__ col,
                                                 const float* __restrict__ ew,
                                                 const int* __restrict__ gscan,
                                                 int2* __restrict__ sorted) {
    __shared__ int lcur[NB];
    int t = threadIdx.x;
    if (t < NB) lcur[t] = gscan[t * NBLKA + blockIdx.x];
    __syncthreads();
    int base = blockIdx.x * EPB;
    #pragma unroll
    for (int i = 0; i < 8; ++i) {
        int e = base + i * 256 + t;
        if (e < NE) {
            int c = col[e];
            int pos = atomicAdd(&lcur[c >> BSH], 1);
            sorted[pos] = make_int2(row[e] | ((c & 511) << 17), __float_as_int(ew[e]));
        }
    }
}

// ---------------- pass B: per-bucket fine CSR (512 cols, LDS count+scan) ------
__global__ __launch_bounds__(SB) void k_bcsr(const int2* __restrict__ sorted,
                                             const int* __restrict__ gscan,
                                             int* __restrict__ rowstart,
                                             int2* __restrict__ csr) {
    __shared__ int lcnt[SB];
    __shared__ int lscan[SB];
    int t = threadIdx.x, b = blockIdx.x;
    int base = gscan[b * NBLKA];
    int end  = (b == NB - 1) ? NE : gscan[(b + 1) * NBLKA];
    lcnt[t] = 0;
    __syncthreads();
    for (int e = base + t; e < end; e += SB)
        atomicAdd(&lcnt[sorted[e].x >> 17], 1);
    __syncthreads();
    int v = lcnt[t];
    lscan[t] = v;
    __syncthreads();
    for (int off = 1; off < SB; off <<= 1) {
        int u = (t >= off) ? lscan[t - off] : 0;
        __syncthreads();
        lscan[t] += u;
        __syncthreads();
    }
    int ex = lscan[t] - v;           // exclusive scan within bucket
    int idx = b * SB + t;
    if (idx <= NN) rowstart[idx] = base + ex;
    lcnt[t] = base + ex;             // cursor
    __syncthreads();
    for (int e = base + t; e < end; e += SB) {
        int2 p = sorted[e];
        int slot = atomicAdd(&lcnt[p.x >> 17], 1);
        csr[slot] = make_int2(p.x & 0x1FFFF, p.y);
    }
}

// ---------------- per-node degree: 16 lanes per node, coalesced ---------------
__global__ __launch_bounds__(256) void k_rowdeg(const int2* __restrict__ csr,
                                                const int* __restrict__ rowstart,
                                                float* __restrict__ dis) {
    int t = threadIdx.x;
    int node = blockIdx.x * 16 + (t >> 4);   // NN % 16 == 0
    int f = t & 15;
    int e0 = rowstart[node], e1 = rowstart[node + 1];
    float d = 0.f;
    for (int e = e0 + f; e < e1; e += 16) d += __int_as_float(csr[e].y);
    d += __shfl_xor(d, 1);
    d += __shfl_xor(d, 2);
    d += __shfl_xor(d, 4);
    d += __shfl_xor(d, 8);
    if (f == 0) dis[node] = (d > 0.f) ? (1.0f / sqrtf(d)) : 0.f;
}

// ---------------- csr weight: ew -> dis[src]*ew*dis[dst], coalesced -----------
__global__ __launch_bounds__(256) void k_rownorm(int2* __restrict__ csr,
                                                 const int* __restrict__ rowstart,
                                                 const float* __restrict__ dis) {
    int t = threadIdx.x;
    int node = blockIdx.x * 16 + (t >> 4);
    int f = t & 15;
    int e0 = rowstart[node], e1 = rowstart[node + 1];
    float dc = dis[node];
    for (int e = e0 + f; e < e1; e += 16) {
        int2 p = csr[e];
        float w = dis[p.x] * __int_as_float(p.y) * dc;
        csr[e] = make_int2(p.x, __float_as_int(w));
    }
}

// ---------------- conv weight split into pre-swizzled MFMA fragments ----------
// frag layout: [layer][ct:4][kh:2][h:2][lane:64][j:8] bf16
__global__ void k_wsplit(const float* __restrict__ conv_w, ushort* __restrict__ wf) {
    int tid = blockIdx.x * blockDim.x + threadIdx.x;   // 4*4*2*64*8 = 16384
    int j = tid & 7;
    int lane = (tid >> 3) & 63;
    int kh = (tid >> 9) & 1;
    int ct = (tid >> 10) & 3;
    int l = tid >> 12;
    int k = kh * 32 + (lane >> 4) * 8 + j;
    int n = ct * 16 + (lane & 15);
    float w = conv_w[l * D * D + k * D + n];
    ushort hi = f2bf(w);
    ushort lo = f2bf(w - bf2f(hi));
    int base = (((l * 4 + ct) * 2 + kh) * 2) * 512 + lane * 8 + j;
    wf[base] = hi;            // h=0
    wf[base + 512] = lo;      // h=1
}

// ---------------- lin0 weight split: [ct:4][ks:4][h:2][lane:64][j:8], K pad 128
__global__ void k_wsplit0(const float* __restrict__ w, ushort* __restrict__ wf) {
    int tid = blockIdx.x * blockDim.x + threadIdx.x;   // 4*4*64*8 = 8192
    int j = tid & 7;
    int lane = (tid >> 3) & 63;
    int ks = (tid >> 9) & 3;
    int ct = tid >> 11;
    int k = ks * 32 + (lane >> 4) * 8 + j;
    int n = ct * 16 + (lane & 15);
    float v = (k < FIN) ? w[k * D + n] : 0.f;
    ushort hi = f2bf(v);
    ushort lo = f2bf(v - bf2f(hi));
    int base = ((ct * 4 + ks) * 2) * 512 + lane * 8 + j;
    wf[base] = hi;
    wf[base + 512] = lo;
}

// ---------------- lin0 via MFMA: out = relu(x @ W0 + b0) -> bf16 rows ---------
__global__ __launch_bounds__(256) void k_lin0_mfma(const float* __restrict__ x,
                                                   const ushort* __restrict__ wf,
                                                   const float* __restrict__ b,
                                                   ushort* __restrict__ out) {
    __shared__ ushort xhi[64 * LSTR];   // 17.4 KB
    __shared__ ushort xlo[64 * LSTR];   // 17.4 KB
    int t = threadIdx.x;
    int r0 = blockIdx.x * 64;
    for (int i = t; i < 1600; i += 256) {           // 64 rows x 25 float4
        int r = i / 25, c4 = i - (i / 25) * 25;
        float4 v = {0.f, 0.f, 0.f, 0.f};
        if (r0 + r < NN)
            v = *reinterpret_cast<const float4*>(&x[(size_t)(r0 + r) * FIN + c4 * 4]);
        int base = r * LSTR + c4 * 4;
        ushort h;
        h = f2bf(v.x); xhi[base + 0] = h; xlo[base + 0] = f2bf(v.x - bf2f(h));
        h = f2bf(v.y); xhi[base + 1] = h; xlo[base + 1] = f2bf(v.y - bf2f(h));
        h = f2bf(v.z); xhi[base + 2] = h; xlo[base + 2] = f2bf(v.z - bf2f(h));
        h = f2bf(v.w); xhi[base + 3] = h; xlo[base + 3] = f2bf(v.w - bf2f(h));
    }
    for (int i = t; i < 64 * 28; i += 256) {        // zero-pad k = 100..127
        int r = i / 28, c = FIN + (i - (i / 28) * 28);
        xhi[r * LSTR + c] = 0;
        xlo[r * LSTR + c] = 0;
    }
    __syncthreads();
    int wave = t >> 6, lane = t & 63;
    int lrow = wave * 16 + (lane & 15);
    bf16x8 ahi[4], alo[4];
    #pragma unroll
    for (int ks = 0; ks < 4; ++ks) {
        int off = lrow * LSTR + ks * 32 + (lane >> 4) * 8;
        ahi[ks] = *reinterpret_cast<const bf16x8*>(&xhi[off]);
        alo[ks] = *reinterpret_cast<const bf16x8*>(&xlo[off]);
    }
    float bv[4];
    #pragma unroll
    for (int ct = 0; ct < 4; ++ct) bv[ct] = b[ct * 16 + (lane & 15)];
    int r = r0 + wave * 16;
    f32x4 acc[4];
    #pragma unroll
    for (int ct = 0; ct < 4; ++ct) {
        acc[ct] = {bv[ct], bv[ct], bv[ct], bv[ct]};
        #pragma unroll
        for (int ks = 0; ks < 4; ++ks) {
            int base = ((ct * 4 + ks) * 2) * 512 + lane * 8;
            bf16x8 wh = *reinterpret_cast<const bf16x8*>(&wf[base]);
            bf16x8 wl = *reinterpret_cast<const bf16x8*>(&wf[base + 512]);
            acc[ct] = __builtin_amdgcn_mfma_f32_16x16x32_bf16(ahi[ks], wh, acc[ct], 0, 0, 0);
            acc[ct] = __builtin_amdgcn_mfma_f32_16x16x32_bf16(ahi[ks], wl, acc[ct], 0, 0, 0);
            acc[ct] = __builtin_amdgcn_mfma_f32_16x16x32_bf16(alo[ks], wh, acc[ct], 0, 0, 0);
        }
    }
    #pragma unroll
    for (int ct = 0; ct < 4; ++ct) {
        int ocol = ct * 16 + (lane & 15);
        #pragma unroll
        for (int i = 0; i < 4; ++i) {
            int orow = r + (lane >> 4) * 4 + i;
            if (orow < NN) out[orow * D + ocol] = f2bf(fmaxf(acc[ct][i], 0.f));
        }
    }
}

// ---------------- FUSED conv: CSR gather-aggregate + MFMA matmul + bias + relu
// block = 16 nodes (4 waves x 4 nodes). Gather identical to previous k_agg
// (4-deep csr prefetch). Aggregated rows staged bf16 in LDS; after barrier
// wave w computes output col-tile ct=w of the 16-row MFMA and stores.
__global__ __launch_bounds__(256, 8) void k_conv_fused(const ushort* __restrict__ src,
                                                       const int* __restrict__ rowstart,
                                                       const int2* __restrict__ csr,
                                                       const ushort* __restrict__ wf,
                                                       const float* __restrict__ bias,
                                                       ushort* __restrict__ dst) {
    __shared__ ushort arow[16 * ASTR];   // 2.3 KB, stride 144B (16B-aligned, 2-way max)
    int t = threadIdx.x;
    int wave = t >> 6, lane = t & 63;
    int g = lane >> 4;          // node sub-index within wave
    int f = lane & 15;          // feature quad
    int rloc = wave * 4 + g;    // local row 0..15
    int node = blockIdx.x * 16 + rloc;   // NN % 16 == 0
    int e0 = rowstart[node], e1 = rowstart[node + 1];
    float4 acc = {0.f, 0.f, 0.f, 0.f};
    int2 p0, p1, p2, p3;
    {
        int a0 = e0 + 0 < e1 ? e0 + 0 : 0;
        int a1 = e0 + 1 < e1 ? e0 + 1 : 0;
        int a2 = e0 + 2 < e1 ? e0 + 2 : 0;
        int a3 = e0 + 3 < e1 ? e0 + 3 : 0;
        p0 = csr[a0]; p1 = csr[a1]; p2 = csr[a2]; p3 = csr[a3];
    }
    for (int base = e0; base < e1; base += 4) {
        int n0 = base + 4 < e1 ? base + 4 : 0;
        int n1 = base + 5 < e1 ? base + 5 : 0;
        int n2 = base + 6 < e1 ? base + 6 : 0;
        int n3 = base + 7 < e1 ? base + 7 : 0;
        int2 q0 = csr[n0], q1 = csr[n1], q2 = csr[n2], q3 = csr[n3];
        float w0 = (base + 0 < e1) ? __int_as_float(p0.y) : 0.f;
        float w1 = (base + 1 < e1) ? __int_as_float(p1.y) : 0.f;
        float w2 = (base + 2 < e1) ? __int_as_float(p2.y) : 0.f;
        float w3 = (base + 3 < e1) ? __int_as_float(p3.y) : 0.f;
        uint2 v0 = *reinterpret_cast<const uint2*>(&src[p0.x * D + f * 4]);
        uint2 v1 = *reinterpret_cast<const uint2*>(&src[p1.x * D + f * 4]);
        uint2 v2 = *reinterpret_cast<const uint2*>(&src[p2.x * D + f * 4]);
        uint2 v3 = *reinterpret_cast<const uint2*>(&src[p3.x * D + f * 4]);
        acc.x = fmaf(bflo(v0.x), w0, acc.x); acc.y = fmaf(bfhi(v0.x), w0, acc.y);
        acc.z = fmaf(bflo(v0.y), w0, acc.z); acc.w = fmaf(bfhi(v0.y), w0, acc.w);
        acc.x = fmaf(bflo(v1.x), w1, acc.x); acc.y = fmaf(bfhi(v1.x), w1, acc.y);
        acc.z = fmaf(bflo(v1.y), w1, acc.z); acc.w = fmaf(bfhi(v1.y), w1, acc.w);
        acc.x = fmaf(bflo(v2.x), w2, acc.x); acc.y = fmaf(bfhi(v2.x), w2, acc.y);
        acc.z = fmaf(bflo(v2.y), w2, acc.z); acc.w = fmaf(bfhi(v2.y), w2, acc.w);
        acc.x = fmaf(bflo(v3.x), w3, acc.x); acc.y = fmaf(bfhi(v3.x), w3, acc.y);
        acc.z = fmaf(bflo(v3.y), w3, acc.z); acc.w = fmaf(bfhi(v3.y), w3, acc.w);
        p0 = q0; p1 = q1; p2 = q2; p3 = q3;
    }
    // stage aggregated row (bf16) into LDS tile
    uint2 o;
    o.x = (uint)f2bf(acc.x) | ((uint)f2bf(acc.y) << 16);
    o.y = (uint)f2bf(acc.z) | ((uint)f2bf(acc.w) << 16);
    *reinterpret_cast<uint2*>(&arow[rloc * ASTR + f * 4]) = o;
    __syncthreads();
    // MFMA tail: wave computes col-tile ct = wave
    int ct = wave;
    int base0 = ((ct * 2 + 0) * 2) * 512 + lane * 8;   // kh=0
    int base1 = ((ct * 2 + 1) * 2) * 512 + lane * 8;   // kh=1
    bf16x8 wh0 = *reinterpret_cast<const bf16x8*>(&wf[base0]);
    bf16x8 wl0 = *reinterpret_cast<const bf16x8*>(&wf[base0 + 512]);
    bf16x8 wh1 = *reinterpret_cast<const bf16x8*>(&wf[base1]);
    bf16x8 wl1 = *reinterpret_cast<const bf16x8*>(&wf[base1 + 512]);
    int arow_idx = lane & 15;
    bf16x8 a0 = *reinterpret_cast<const bf16x8*>(&arow[arow_idx * ASTR + (lane >> 4) * 8]);
    bf16x8 a1 = *reinterpret_cast<const bf16x8*>(&arow[arow_idx * ASTR + 32 + (lane >> 4) * 8]);
    float bv = bias[ct * 16 + (lane & 15)];
    f32x4 c = {bv, bv, bv, bv};
    c = __builtin_amdgcn_mfma_f32_16x16x32_bf16(a0, wh0, c, 0, 0, 0);
    c = __builtin_amdgcn_mfma_f32_16x16x32_bf16(a1, wh1, c, 0, 0, 0);
    c = __builtin_amdgcn_mfma_f32_16x16x32_bf16(a0, wl0, c, 0, 0, 0);
    c = __builtin_amdgcn_mfma_f32_16x16x32_bf16(a1, wl1, c, 0, 0, 0);
    int ocol = ct * 16 + (lane & 15);
    int r0 = blockIdx.x * 16;
    #pragma unroll
    for (int i = 0; i < 4; ++i) {
        int orow = r0 + (lane >> 4) * 4 + i;
        dst[orow * D + ocol] = f2bf(fmaxf(c[i], 0.f));
    }
}

// ---------------- segmented mean-pool over sorted batch (bf16 src) ------------
__global__ __launch_bounds__(256) void k_pool(const ushort* __restrict__ src,
                                              const int* __restrict__ batch,
                                              float* __restrict__ pooled,
                                              float* __restrict__ cnt) {
    int wave = threadIdx.x >> 6, lane = threadIdx.x & 63;
    int n0 = blockIdx.x * 64 + wave * 16;
    float s = 0.f;
    int curg = -1, runlen = 0;
    for (int i = 0; i < 16; ++i) {
        int node = n0 + i;
        if (node >= NN) break;
        int gg = batch[node];
        if (gg != curg) {
            if (curg >= 0) {
                atomicAdd(&pooled[curg * D + lane], s);
                if (lane == 0) atomicAdd(&cnt[curg], (float)runlen);
            }
            curg = gg; s = 0.f; runlen = 0;
        }
        s += bf2f(src[node * D + lane]);
        ++runlen;
    }
    if (curg >= 0) {
        atomicAdd(&pooled[curg * D + lane], s);
        if (lane == 0) atomicAdd(&cnt[curg], (float)runlen);
    }
}

// ---------------- MLP head: one block per graph ----------------
__global__ __launch_bounds__(64) void k_head(const float* __restrict__ pooled,
                                             const float* __restrict__ cnt,
                                             const float* __restrict__ lin1_w,
                                             const float* __restrict__ lin1_b,
                                             const float* __restrict__ fc_w,
                                             const float* __restrict__ fc_b,
                                             const float* __restrict__ lin2_w,
                                             const float* __restrict__ lin2_b,
                                             float* __restrict__ out) {
    __shared__ float buf0[D], buf1[D];
    int g = blockIdx.x, d = threadIdx.x;
    float c = fmaxf(cnt[g], 1.0f);
    buf0[d] = pooled[g * D + d] / c;
    __syncthreads();
    float acc = lin1_b[d];
    #pragma unroll
    for (int k = 0; k < D; ++k) acc += buf0[k] * lin1_w[k * D + d];
    buf1[d] = fmaxf(acc, 0.f);
    __syncthreads();
    acc = fc_b[d];
    #pragma unroll
    for (int k = 0; k < D; ++k) acc += buf1[k] * fc_w[k * D + d];
    buf0[d] = fmaxf(acc, 0.f);
    __syncthreads();
    acc = fc_b[D + d];
    #pragma unroll
    for (int k = 0; k < D; ++k) acc += buf0[k] * fc_w[D * D + k * D + d];
    buf1[d] = fmaxf(acc, 0.f);
    __syncthreads();
    float v = buf1[d] * lin2_w[d];
    #pragma unroll
    for (int off = 32; off; off >>= 1) v += __shfl_down(v, off);
    if (d == 0) out[g] = v + lin2_b[0];
}

extern "C" void kernel_launch(void* const* d_in, const int* in_sizes, int n_in,
                              void* d_out, int out_size, void* d_ws, size_t ws_size,
                              hipStream_t stream) {
    const float* x      = (const float*)d_in[0];
    const int*   ei     = (const int*)  d_in[1];
    const float* ew     = (const float*)d_in[2];
    const int*   batch  = (const int*)  d_in[3];
    const float* lin0_w = (const float*)d_in[4];
    const float* lin0_b = (const float*)d_in[5];
    const float* conv_w = (const float*)d_in[6];
    const float* conv_b = (const float*)d_in[7];
    const float* lin1_w = (const float*)d_in[8];
    const float* lin1_b = (const float*)d_in[9];
    const float* fc_w   = (const float*)d_in[10];
    const float* fc_b   = (const float*)d_in[11];
    const float* lin2_w = (const float*)d_in[12];
    const float* lin2_b = (const float*)d_in[13];
    float* out = (float*)d_out;

    const int* rowv = ei;
    const int* colv = ei + NE;

    // workspace layout (~53 MB)
    ushort* bufA    = (ushort*)d_ws;                  // N*D bf16 (12.8 MB)
    ushort* bufB    = bufA + (size_t)NN * D;          // N*D bf16
    ushort* bufG    = bufB + (size_t)NN * D;          // N*D bf16 (build scratch)
    int2*   csr     = (int2*)(bufG + (size_t)NN * D); // E (src, weight-bits)
    int*   rowstart = (int*)(csr + NE);               // N+1
    float* dis      = (float*)(rowstart + NN + 1);    // N
    float* pooled   = dis + NN;                       // G*D
    float* cnt      = pooled + NG * D;                // G
    ushort* wfrags  = (ushort*)(cnt + NG);            // 4*8192 bf16 = 64 KB
    ushort* wfrags0 = wfrags + 4 * 8192;              // 8192*2 bf16 = 32 KB
    // build-phase overlays (dead regions during build):
    int2*  sorted   = (int2*)bufG;                    // E * 8B == N*D*2B exactly
    int*   ghist    = (int*)bufB;                     // NSCAN ints (613 KB)
    int*   gscan    = ghist + NSCAN;                  // NSCAN ints
    int*   bsums    = gscan + NSCAN;                  // NBLKS ints

    hipMemsetAsync(pooled, 0, (NG * D + NG) * sizeof(float), stream);

    // ---- atomic-free CSR build (LDS multisplit counting sort) ----
    k_hist<<<NBLKA, 256, 0, stream>>>(colv, ghist);
    s_scan1<<<NBLKS, SB, 0, stream>>>(ghist, gscan, bsums, NSCAN);
    s_scan2<<<1, SB, 0, stream>>>(bsums, NBLKS);
    s_scan3<<<NBLKS, SB, 0, stream>>>(gscan, bsums, NSCAN);
    k_scatter<<<NBLKA, 256, 0, stream>>>(rowv, colv, ew, gscan, sorted);
    k_bcsr<<<NB, SB, 0, stream>>>(sorted, gscan, rowstart, csr);

    k_rowdeg<<<NN / 16, 256, 0, stream>>>(csr, rowstart, dis);
    k_rownorm<<<NN / 16, 256, 0, stream>>>(csr, rowstart, dis);
    k_wsplit<<<64, 256, 0, stream>>>(conv_w, wfrags);
    k_wsplit0<<<32, 256, 0, stream>>>(lin0_w, wfrags0);

    k_lin0_mfma<<<(NN + 63) / 64, 256, 0, stream>>>(x, wfrags0, lin0_b, bufA);

    int cg = NN / 16;
    k_conv_fused<<<cg, 256, 0, stream>>>(bufA, rowstart, csr, wfrags + 0 * 8192,
                                         conv_b + 0 * D, bufB);
    k_conv_fused<<<cg, 256, 0, stream>>>(bufB, rowstart, csr, wfrags + 1 * 8192,
                                         conv_b + 1 * D, bufA);
    k_conv_fused<<<cg, 256, 0, stream>>>(bufA, rowstart, csr, wfrags + 2 * 8192,
                                         conv_b + 2 * D, bufB);
    k_conv_fused<<<cg, 256, 0, stream>>>(bufB, rowstart, csr, wfrags + 3 * 8192,
                                         conv_b + 3 * D, bufA);

    k_pool<<<(NN + 63) / 64, 256, 0, stream>>>(bufA, batch, pooled, cnt);
    k_head<<<NG, 64, 0, stream>>>(pooled, cnt, lin1_w, lin1_b, fc_w, fc_b,
                                  lin2_w, lin2_b, out);
}